// Round 5
// baseline (364.577 us; speedup 1.0000x reference)
//
#include <hip/hip_runtime.h>
#include <math.h>

// ---- problem constants ----
constexpr int N_  = 2048;
constexpr int T_  = 1024;
constexpr int E_  = 16384;
constexpr int B_  = 32;
constexpr int C1_ = 8,  C2_ = 16, C3_ = 32;
constexpr int K1_ = 25, K2_ = 15, K3_ = 7;
constexpr int T2_ = 61;           // conv3+pool output length
constexpr int D_  = 128;
constexpr float EPS_ = 1e-5f;
constexpr int M2_ = K2_ + 3;      // 18 fused taps (conv2 ⊗ pool4)
constexpr int H3E_ = T2_ * C3_;   // 1952 elems/node after conv stack
constexpr int HGE_ = T2_ * D_;    // 7808 elems/node in GCN space
constexpr int M_   = N_ * T2_;    // 124928 flattened GEMM rows (= 976*128)

typedef __attribute__((ext_vector_type(4))) float f32x4;
typedef __attribute__((ext_vector_type(8))) short bf16x8;

__device__ __forceinline__ unsigned short f2bf(float f) {
    unsigned int u = __float_as_uint(f);
    unsigned int r = (u + 0x7fffu + ((u >> 16) & 1u)) >> 16;
    return (unsigned short)r;
}
__device__ __forceinline__ float bf2f(unsigned short s) {
    return __uint_as_float((unsigned int)s << 16);
}

// ====== k_setup: BN-fold weights + MFMA layouts + full CSR graph build (1 block) ======
__global__ __launch_bounds__(256) void k_setup(
        const float* __restrict__ c1w, const float* __restrict__ c1b,
        const float* __restrict__ g1, const float* __restrict__ b1,
        const float* __restrict__ c2w, const float* __restrict__ c2b,
        const float* __restrict__ g2, const float* __restrict__ b2,
        const float* __restrict__ c3w, const float* __restrict__ c3b,
        const float* __restrict__ g3, const float* __restrict__ b3,
        const float* __restrict__ w1, const float* __restrict__ w2,
        const int* __restrict__ ei, const int* __restrict__ batch,
        float* __restrict__ wf1t, float* __restrict__ bf1,
        unsigned short* __restrict__ wB2, float* __restrict__ bf2c,
        unsigned short* __restrict__ wB3, float* __restrict__ bf3c,
        unsigned short* __restrict__ wt1, unsigned short* __restrict__ wt2,
        int* __restrict__ offs, int* __restrict__ count, float* __restrict__ dinv,
        int* __restrict__ csr, int* __restrict__ cnt,
        float* __restrict__ lacc, int* __restrict__ done) {
    __shared__ int cntL[N_];
    __shared__ int offL[N_];
    __shared__ int part[256];
    __shared__ int bcnt[B_];
    int tid = threadIdx.x;
    const float rs = rsqrtf(1.f + EPS_);
    for (int i = tid; i < N_; i += 256) cntL[i] = 0;
    if (tid < B_) bcnt[tid] = 0;
    if (tid < B_ * 4) lacc[tid] = 0.f;
    if (tid == 0) *done = 0;
    __syncthreads();
    // ---- counts ----
#pragma unroll
    for (int it = 0; it < E_ / 256; ++it) atomicAdd(&cntL[ei[E_ + tid + 256 * it]], 1);
#pragma unroll
    for (int it = 0; it < N_ / 256; ++it) atomicAdd(&bcnt[batch[tid + 256 * it]], 1);
    __syncthreads();
    // ---- scan (8 per thread) ----
    {
        int loc[8];
        int s = 0;
        int base = tid * 8;
#pragma unroll
        for (int j = 0; j < 8; ++j) { loc[j] = cntL[base + j]; s += loc[j]; }
        part[tid] = s;
        __syncthreads();
        for (int o = 1; o < 256; o <<= 1) {
            int add = (tid >= o) ? part[tid - o] : 0;
            __syncthreads();
            part[tid] += add;
            __syncthreads();
        }
        int run = part[tid] - s;
#pragma unroll
        for (int j = 0; j < 8; ++j) {
            offL[base + j] = run;
            offs[base + j] = run;
            count[base + j] = loc[j];
            dinv[base + j] = rsqrtf((float)(loc[j] + 1));
            run += loc[j];
        }
        if (tid < B_) cnt[tid] = bcnt[tid];
    }
    __syncthreads();
    for (int i = tid; i < N_; i += 256) cntL[i] = offL[i];  // cursors
    __syncthreads();
    // ---- fill ----
#pragma unroll
    for (int it = 0; it < E_ / 256; ++it) {
        int e = tid + 256 * it;
        int d = ei[E_ + e], src = ei[e];
        int p = atomicAdd(&cntL[d], 1);
        csr[p] = src;
    }
    // ---- weight prep (independent of graph) ----
    // wf1t[k*8 + c]
    for (int i = tid; i < C1_ * K1_; i += 256) {
        int k = i >> 3, c = i & 7;
        wf1t[i] = c1w[c * K1_ + k] * g1[c] * rs;
    }
    if (tid < C1_) bf1[tid] = c1b[tid] * g1[tid] * rs + b1[tid];
    // wB2[g][c2][ph*8+c1]: fused conv2 taps m=4g+ph (0 if m>=18)
    for (int i = tid; i < 5 * C2_ * 32; i += 256) {
        int g = i >> 9, rem = i & 511;
        int c2 = rem >> 5, k32 = rem & 31;
        int ph = k32 >> 3, c1 = k32 & 7;
        int m = 4 * g + ph;
        float s = 0.f;
        if (m < M2_) {
            for (int k = 0; k < K2_; ++k) { int d = m - k; if (d >= 0 && d <= 3) s += c2w[(c2 * C1_ + c1) * K2_ + k]; }
            s *= g2[c2] * rs * 0.25f;
        }
        wB2[i] = f2bf(s);
    }
    if (tid < C2_) bf2c[tid] = c2b[tid] * g2[tid] * rs + b2[tid];
    // wB3[g][c3][mloc*16+c2]: fused conv3 taps m=2g+mloc
    for (int i = tid; i < 5 * C3_ * 32; i += 256) {
        int g = i >> 10, rem = i & 1023;
        int c3 = rem >> 5, j = rem & 31;
        int c2 = j & 15, mloc = j >> 4;
        int m = 2 * g + mloc;
        float s = 0.f;
        for (int k = 0; k < K3_; ++k) { int d = m - k; if (d >= 0 && d <= 3) s += c3w[(c3 * C2_ + c2) * K3_ + k]; }
        wB3[i] = f2bf(s * g3[c3] * rs * 0.25f);
    }
    if (tid < C3_) bf3c[tid] = c3b[tid] * g3[tid] * rs + b3[tid];
    // wt1[d][c] (128x32), wt2[d2][d1] (128x128)
    for (int i = tid; i < C3_ * D_; i += 256) { int d = i >> 5, c = i & 31; wt1[i] = f2bf(w1[c * D_ + d]); }
    for (int i = tid; i < D_ * D_; i += 256) { int d2 = i >> 7, d1 = i & 127; wt2[i] = f2bf(w2[d1 * D_ + d2]); }
}

// ====== mega-fused conv stack: pe-MLP + conv1 VALU -> conv2 MFMA -> conv3 MFMA ======
// xs2[u][ph*8+c1] = conv1(t=4u+ph, c1)            (80B rows)
// xs3[u][ph*16+c2] = relu(conv2+pool)(p=4u+ph,c2) (144B rows)
// h3[n][t][c3] = relu(conv3+pool) + pe            (global bf16)
__global__ __launch_bounds__(256) void k_conv123(const float* __restrict__ x,
        const float* __restrict__ pos,
        const float* __restrict__ pw1, const float* __restrict__ pb1,
        const float* __restrict__ pw2, const float* __restrict__ pb2,
        const float* __restrict__ wf1t, const float* __restrict__ bf1,
        const unsigned short* __restrict__ wB2g, const float* __restrict__ bf2c,
        const unsigned short* __restrict__ wB3g, const float* __restrict__ bf3c,
        unsigned short* __restrict__ h3) {
    __shared__ __align__(16) float xin[T_ + 32];               // 1056 f32 (halo 12 + pad)
    __shared__ __align__(16) float wl1[C1_ * K1_];             // 200
    __shared__ __align__(16) unsigned short xs2[260 * 40];     // 20.8 KB
    __shared__ __align__(16) unsigned short xs3[66 * 72];      // 9.5 KB
    __shared__ float hid[32], pes[32];
    int n = blockIdx.x, tid = threadIdx.x;
    int wid = tid >> 6, lane = tid & 63;
    int lrow = lane & 15, lk = lane >> 4;
    // ---- stage ----
    for (int i = tid; i < T_ + 32; i += 256) {
        int gi = i - 12;
        xin[i] = (gi >= 0 && gi < T_) ? x[n * T_ + gi] : 0.f;
    }
    if (tid < C1_ * K1_) wl1[tid] = wf1t[tid];
    if (tid < 32) {
        float p0 = pos[n * 3], p1 = pos[n * 3 + 1], p2 = pos[n * 3 + 2];
        hid[tid] = fmaxf(p0 * pw1[tid] + p1 * pw1[32 + tid] + p2 * pw1[64 + tid] + pb1[tid], 0.f);
    }
    float bl1r[C1_];
#pragma unroll
    for (int c = 0; c < C1_; ++c) bl1r[c] = bf1[c];
    __syncthreads();
    if (tid < 32) {
        float o = pb2[tid];
#pragma unroll
        for (int cc = 0; cc < 32; ++cc) o += hid[cc] * pw2[cc * 32 + tid];
        pes[tid] = o;
    }
    // ---- conv1 (f32 VALU) -> xs2 bf16 fragments ----
#pragma unroll
    for (int it = 0; it < 4; ++it) {
        int t = tid + 256 * it;
        float a[C1_];
#pragma unroll
        for (int c = 0; c < C1_; ++c) a[c] = bl1r[c];
#pragma unroll
        for (int k = 0; k < K1_; ++k) {
            float xv = xin[t + k];
            const f32x4* wp = (const f32x4*)&wl1[k * C1_];
            f32x4 w0 = wp[0], w1v = wp[1];
#pragma unroll
            for (int j = 0; j < 4; ++j) { a[j] += w0[j] * xv; a[4 + j] += w1v[j] * xv; }
        }
        int u = t >> 2, ph = t & 3;
        bf16x8 sv;
#pragma unroll
        for (int c = 0; c < C1_; ++c) sv[c] = (short)f2bf(fmaxf(a[c], 0.f));
        *(bf16x8*)&xs2[u * 40 + ph * 8] = sv;
    }
    __syncthreads();
    // ---- conv2 via MFMA (B from L2), epilogue -> xs3 fragments ----
    {
        bf16x8 bfr[5];
#pragma unroll
        for (int g = 0; g < 5; ++g)
            bfr[g] = *(const bf16x8*)(wB2g + g * 512 + lrow * 32 + lk * 8);
        float bb = bf2c[lrow];   // c2 = lrow
#pragma unroll
        for (int mt = 0; mt < 4; ++mt) {
            int p0 = (wid * 4 + mt) * 16;
            f32x4 c4 = {0.f, 0.f, 0.f, 0.f};
#pragma unroll
            for (int g = 0; g < 5; ++g) {
                bf16x8 af = *(const bf16x8*)&xs2[(p0 + lrow + g) * 40 + lk * 8];
                c4 = __builtin_amdgcn_mfma_f32_16x16x32_bf16(af, bfr[g], c4, 0, 0, 0);
            }
            int urow = (p0 >> 2) + lk;
#pragma unroll
            for (int r = 0; r < 4; ++r)
                xs3[urow * 72 + r * 16 + lrow] = f2bf(fmaxf(c4[r] + bb, 0.f));
        }
    }
    __syncthreads();
    // ---- conv3 via MFMA (B from L2) + bias + relu + pe -> h3 ----
    {
        int t0 = wid * 16;
        f32x4 acc[2];
        acc[0] = f32x4{0.f, 0.f, 0.f, 0.f};
        acc[1] = f32x4{0.f, 0.f, 0.f, 0.f};
        bf16x8 af[5];
#pragma unroll
        for (int g = 0; g < 5; ++g)
            af[g] = *(const bf16x8*)&xs3[(t0 + lrow + (g >> 1)) * 72 + (g & 1) * 32 + lk * 8];
#pragma unroll
        for (int nn = 0; nn < 2; ++nn) {
#pragma unroll
            for (int g = 0; g < 5; ++g) {
                bf16x8 bf = *(const bf16x8*)(wB3g + g * 1024 + (nn * 16 + lrow) * 32 + lk * 8);
                acc[nn] = __builtin_amdgcn_mfma_f32_16x16x32_bf16(af[g], bf, acc[nn], 0, 0, 0);
            }
        }
#pragma unroll
        for (int nn = 0; nn < 2; ++nn) {
            int c3 = nn * 16 + lrow;
            float b3v = bf3c[c3];
            float pev = pes[c3];
#pragma unroll
            for (int r = 0; r < 4; ++r) {
                int t = t0 + lk * 4 + r;
                if (t < T2_)
                    h3[(size_t)n * H3E_ + t * C3_ + c3] = f2bf(fmaxf(acc[nn][r] + b3v, 0.f) + pev);
            }
        }
    }
}

// ====== gather aggregation layer 1 (bf16 in/out, f32 accum, both dinv folded) ======
template <int NG>
__global__ __launch_bounds__(256) void k_agg_bf(const unsigned short* __restrict__ h,
        const int* __restrict__ off, const int* __restrict__ cnt, const int* __restrict__ csr,
        const float* __restrict__ dinv, unsigned short* __restrict__ out) {
    int n = blockIdx.x, tid = threadIdx.x;
    float acc[8];
    float dn = dinv[n];
    const bf16x8* self = (const bf16x8*)(h + (size_t)n * NG * 8);
    if (tid < NG) {
        bf16x8 v = self[tid];
#pragma unroll
        for (int j = 0; j < 8; ++j) acc[j] = dn * bf2f((unsigned short)v[j]);
    }
    int st = off[n], c = cnt[n];
    for (int i = 0; i < c; ++i) {
        int sn = csr[st + i];
        float f = dinv[sn];
        if (tid < NG) {
            bf16x8 v = ((const bf16x8*)(h + (size_t)sn * NG * 8))[tid];
#pragma unroll
            for (int j = 0; j < 8; ++j) acc[j] += f * bf2f((unsigned short)v[j]);
        }
    }
    if (tid < NG) {
        bf16x8 v;
#pragma unroll
        for (int j = 0; j < 8; ++j) v[j] = (short)f2bf(acc[j] * dn);
        ((bf16x8*)(out + (size_t)n * NG * 8))[tid] = v;
    }
}

// ====== FUSED gemm1+agg2: agg2[n] = dinv[n] * sum_s dinv[s]*relu(agg1[s]@W1+b1) ======
__global__ __launch_bounds__(256) void k_agg_gemm1(const unsigned short* __restrict__ agg1,
        const unsigned short* __restrict__ wt1, const float* __restrict__ bias,
        const int* __restrict__ off, const int* __restrict__ cnt, const int* __restrict__ csr,
        const float* __restrict__ dinv, unsigned short* __restrict__ agg2) {
    int n = blockIdx.x, tid = threadIdx.x;
    int wid = tid >> 6, lane = tid & 63;
    int lrow = lane & 15, lk = lane >> 4;
    bf16x8 bfr[2];
    float bv[2];
#pragma unroll
    for (int nn = 0; nn < 2; ++nn) {
        int col = wid * 32 + nn * 16 + lrow;
        bfr[nn] = *(const bf16x8*)&wt1[col * 32 + lk * 8];
        bv[nn] = bias[col];
    }
    f32x4 acc[4][2];
#pragma unroll
    for (int mt = 0; mt < 4; ++mt)
#pragma unroll
        for (int nn = 0; nn < 2; ++nn) acc[mt][nn] = f32x4{0.f, 0.f, 0.f, 0.f};
    int st = off[n], c = cnt[n];
    for (int i = -1; i < c; ++i) {
        int s = (i < 0) ? n : csr[st + i];
        float f = dinv[s];
        const unsigned short* arow = agg1 + (size_t)s * H3E_;
        bf16x8 af[4];
#pragma unroll
        for (int mt = 0; mt < 4; ++mt)
            af[mt] = *(const bf16x8*)&arow[(mt * 16 + lrow) * 32 + lk * 8];
#pragma unroll
        for (int mt = 0; mt < 4; ++mt) {
#pragma unroll
            for (int nn = 0; nn < 2; ++nn) {
                f32x4 t4 = {0.f, 0.f, 0.f, 0.f};
                t4 = __builtin_amdgcn_mfma_f32_16x16x32_bf16(af[mt], bfr[nn], t4, 0, 0, 0);
#pragma unroll
                for (int r = 0; r < 4; ++r)
                    acc[mt][nn][r] += f * fmaxf(t4[r] + bv[nn], 0.f);
            }
        }
    }
    float dn = dinv[n];
    unsigned short* orow = agg2 + (size_t)n * HGE_;
#pragma unroll
    for (int mt = 0; mt < 4; ++mt) {
#pragma unroll
        for (int r = 0; r < 4; ++r) {
            int t = mt * 16 + lk * 4 + r;
            if (t < T2_) {
#pragma unroll
                for (int nn = 0; nn < 2; ++nn)
                    orow[t * D_ + wid * 32 + nn * 16 + lrow] = f2bf(acc[mt][nn][r] * dn);
            }
        }
    }
}

// ====== MFMA GEMM K=128 + fused dense projection + last-block log_softmax ======
__global__ __launch_bounds__(256) void k_gemm_mfma2f(const unsigned short* __restrict__ A,
        const unsigned short* __restrict__ Bt, const float* __restrict__ bias,
        const float* __restrict__ dw, const int* __restrict__ batch,
        float* __restrict__ lacc, int* __restrict__ done,
        const int* __restrict__ cnt, const float* __restrict__ db,
        float* __restrict__ out) {
    __shared__ float bacc[B_ * 4];
    __shared__ int lastflag;
    int tid = threadIdx.x;
    if (tid < B_ * 4) bacc[tid] = 0.f;
    int blk = blockIdx.x;
    int wid = tid >> 6, lane = tid & 63;
    int wr = wid >> 1, wc = wid & 1;
    int row0 = blk * 128 + wr * 64;
    int col0 = wc * 64;
    int lrow = lane & 15, lk = lane >> 4;
    f32x4 acc[4][4];
#pragma unroll
    for (int m = 0; m < 4; ++m)
#pragma unroll
        for (int nn = 0; nn < 4; ++nn)
#pragma unroll
            for (int r = 0; r < 4; ++r) acc[m][nn][r] = 0.f;
#pragma unroll
    for (int ks = 0; ks < 4; ++ks) {
        bf16x8 a[4], b[4];
#pragma unroll
        for (int m = 0; m < 4; ++m)
            a[m] = *(const bf16x8*)(A + ((size_t)(row0 + m * 16 + lrow)) * D_ + ks * 32 + lk * 8);
#pragma unroll
        for (int nn = 0; nn < 4; ++nn)
            b[nn] = *(const bf16x8*)(Bt + ((size_t)(col0 + nn * 16 + lrow)) * D_ + ks * 32 + lk * 8);
#pragma unroll
        for (int m = 0; m < 4; ++m)
#pragma unroll
            for (int nn = 0; nn < 4; ++nn)
                acc[m][nn] = __builtin_amdgcn_mfma_f32_16x16x32_bf16(a[m], b[nn], acc[m][nn], 0, 0, 0);
    }
    __syncthreads();
    int cur_b = -1;
    f32x4 sacc = {0.f, 0.f, 0.f, 0.f};
#pragma unroll
    for (int m = 0; m < 4; ++m) {
#pragma unroll
        for (int r = 0; r < 4; ++r) {
            int row = row0 + m * 16 + lk * 4 + r;
            int n = row / T2_;
            int t = row - n * T2_;
            int b = batch[n];
            f32x4 s = {0.f, 0.f, 0.f, 0.f};
#pragma unroll
            for (int nn = 0; nn < 4; ++nn) {
                int col = col0 + nn * 16 + lrow;
                float v = fmaxf(acc[m][nn][r] + bias[col], 0.f);
                f32x4 w = *(const f32x4*)(dw + (size_t)(col * T2_ + t) * 4);
                s += v * w;
            }
            if (b != cur_b) {
                if (cur_b >= 0) {
#pragma unroll
                    for (int j = 0; j < 4; ++j) atomicAdd(&bacc[cur_b * 4 + j], sacc[j]);
                }
                cur_b = b;
                sacc = s;
            } else {
                sacc += s;
            }
        }
    }
    if (cur_b >= 0) {
#pragma unroll
        for (int j = 0; j < 4; ++j) atomicAdd(&bacc[cur_b * 4 + j], sacc[j]);
    }
    __syncthreads();
    if (tid < B_ * 4) {
        float v = bacc[tid];
        if (v != 0.f) atomicAdd(&lacc[tid], v);
    }
    __threadfence();
    __syncthreads();
    if (tid == 0) lastflag = (atomicAdd(done, 1) == (int)gridDim.x - 1);
    __syncthreads();
    if (lastflag && tid < B_) {
        float l[4];
#pragma unroll
        for (int j = 0; j < 4; ++j) l[j] = atomicAdd(&lacc[tid * 4 + j], 0.f);  // coherent read
        float inv = 1.f / fmaxf((float)cnt[tid], 1.f);
#pragma unroll
        for (int j = 0; j < 4; ++j) l[j] = l[j] * inv + db[j];
        float m = fmaxf(fmaxf(l[0], l[1]), fmaxf(l[2], l[3]));
        float s = expf(l[0] - m) + expf(l[1] - m) + expf(l[2] - m) + expf(l[3] - m);
        float ls = m + logf(s);
#pragma unroll
        for (int j = 0; j < 4; ++j) out[tid * 4 + j] = l[j] - ls;
    }
}

// ======================= launch =======================
extern "C" void kernel_launch(void* const* d_in, const int* in_sizes, int n_in,
                              void* d_out, int out_size, void* d_ws, size_t ws_size,
                              hipStream_t stream) {
    const float* x       = (const float*)d_in[0];
    const float* pos     = (const float*)d_in[1];
    const float* conv1_w = (const float*)d_in[2];
    const float* conv1_b = (const float*)d_in[3];
    const float* bn1_g   = (const float*)d_in[4];
    const float* bn1_b   = (const float*)d_in[5];
    const float* conv2_w = (const float*)d_in[6];
    const float* conv2_b = (const float*)d_in[7];
    const float* bn2_g   = (const float*)d_in[8];
    const float* bn2_b   = (const float*)d_in[9];
    const float* conv3_w = (const float*)d_in[10];
    const float* conv3_b = (const float*)d_in[11];
    const float* bn3_g   = (const float*)d_in[12];
    const float* bn3_b   = (const float*)d_in[13];
    const float* pos_w1  = (const float*)d_in[14];
    const float* pos_b1  = (const float*)d_in[15];
    const float* pos_w2  = (const float*)d_in[16];
    const float* pos_b2  = (const float*)d_in[17];
    const float* gcn1_w  = (const float*)d_in[18];
    const float* gcn1_b  = (const float*)d_in[19];
    const float* gcn2_w  = (const float*)d_in[20];
    const float* gcn2_b  = (const float*)d_in[21];
    const float* dense_w = (const float*)d_in[22];
    const float* dense_b = (const float*)d_in[23];
    const int*   eidx    = (const int*)d_in[24];
    const int*   batch   = (const int*)d_in[25];
    float* out = (float*)d_out;
    char* ws = (char*)d_ws;

    size_t off = 0;
    auto alloc = [&](size_t bytes) { size_t o = off; off += (bytes + 255) & ~(size_t)255; return o; };
    size_t o_h3     = alloc((size_t)N_ * H3E_ * 2);              // 8 MB bf16
    size_t o_agg1   = alloc(((size_t)N_ * H3E_ + 2048) * 2);     // 8 MB bf16 (+slack)
    size_t o_agg2   = alloc((size_t)N_ * HGE_ * 2);              // 32 MB bf16
    size_t o_lacc   = alloc((size_t)B_ * 4 * 4);
    size_t o_done   = alloc(256);
    size_t o_count  = alloc((size_t)N_ * 4);
    size_t o_off    = alloc((size_t)N_ * 4);
    size_t o_dinv   = alloc((size_t)N_ * 4);
    size_t o_csr    = alloc((size_t)E_ * 4);
    size_t o_cnt    = alloc((size_t)B_ * 4);
    size_t o_wf1t   = alloc((size_t)C1_ * K1_ * 4);
    size_t o_bf1    = alloc((size_t)C1_ * 4);
    size_t o_wB2    = alloc((size_t)5 * C2_ * 32 * 2);
    size_t o_bf2c   = alloc((size_t)C2_ * 4);
    size_t o_wB3    = alloc((size_t)5 * C3_ * 32 * 2);
    size_t o_bf3c   = alloc((size_t)C3_ * 4);
    size_t o_wt1    = alloc((size_t)C3_ * D_ * 2);
    size_t o_wt2    = alloc((size_t)D_ * D_ * 2);

    unsigned short* h3   = (unsigned short*)(ws + o_h3);
    unsigned short* agg1 = (unsigned short*)(ws + o_agg1);
    unsigned short* agg2 = (unsigned short*)(ws + o_agg2);
    float* lacc   = (float*)(ws + o_lacc);
    int*   done   = (int*)(ws + o_done);
    int*   count  = (int*)(ws + o_count);
    int*   offs   = (int*)(ws + o_off);
    float* dinv   = (float*)(ws + o_dinv);
    int*   csr    = (int*)(ws + o_csr);
    int*   cnt    = (int*)(ws + o_cnt);
    float* wf1t   = (float*)(ws + o_wf1t);
    float* bf1    = (float*)(ws + o_bf1);
    unsigned short* wB2 = (unsigned short*)(ws + o_wB2);
    float* bf2c   = (float*)(ws + o_bf2c);
    unsigned short* wB3 = (unsigned short*)(ws + o_wB3);
    float* bf3c   = (float*)(ws + o_bf3c);
    unsigned short* wt1 = (unsigned short*)(ws + o_wt1);
    unsigned short* wt2 = (unsigned short*)(ws + o_wt2);

    k_setup<<<1, 256, 0, stream>>>(conv1_w, conv1_b, bn1_g, bn1_b,
                                   conv2_w, conv2_b, bn2_g, bn2_b,
                                   conv3_w, conv3_b, bn3_g, bn3_b,
                                   gcn1_w, gcn2_w, eidx, batch,
                                   wf1t, bf1, wB2, bf2c, wB3, bf3c, wt1, wt2,
                                   offs, count, dinv, csr, cnt, lacc, done);
    k_conv123<<<N_, 256, 0, stream>>>(x, pos, pos_w1, pos_b1, pos_w2, pos_b2,
                                      wf1t, bf1, wB2, bf2c, wB3, bf3c, h3);
    k_agg_bf<H3E_ / 8><<<N_, 256, 0, stream>>>(h3, offs, count, csr, dinv, agg1);
    k_agg_gemm1<<<N_, 256, 0, stream>>>(agg1, wt1, gcn1_b, offs, count, csr, dinv, agg2);
    k_gemm_mfma2f<<<M_ / 128, 256, 0, stream>>>(agg2, wt2, gcn2_b, dense_w, batch,
                                                lacc, done, cnt, dense_b, out);
}

// Round 6
// 265.737 us; speedup vs baseline: 1.3719x; 1.3719x over previous
//
#include <hip/hip_runtime.h>
#include <math.h>

// ---- problem constants ----
constexpr int N_  = 2048;
constexpr int T_  = 1024;
constexpr int E_  = 16384;
constexpr int B_  = 32;
constexpr int C1_ = 8,  C2_ = 16, C3_ = 32;
constexpr int K1_ = 25, K2_ = 15, K3_ = 7;
constexpr int T2_ = 61;           // conv3+pool output length
constexpr int D_  = 128;
constexpr float EPS_ = 1e-5f;
constexpr int M2_ = K2_ + 3;      // 18 fused taps (conv2 ⊗ pool4)
constexpr int H3E_ = T2_ * C3_;   // 1952 elems/node after conv stack
constexpr int HGE_ = T2_ * D_;    // 7808 elems/node in GCN space
constexpr int M_   = N_ * T2_;    // 124928 flattened GEMM rows (= 976*128)

typedef __attribute__((ext_vector_type(4))) float f32x4;
typedef __attribute__((ext_vector_type(8))) short bf16x8;

__device__ __forceinline__ unsigned short f2bf(float f) {
    unsigned int u = __float_as_uint(f);
    unsigned int r = (u + 0x7fffu + ((u >> 16) & 1u)) >> 16;
    return (unsigned short)r;
}
__device__ __forceinline__ float bf2f(unsigned short s) {
    return __uint_as_float((unsigned int)s << 16);
}

// ====== k_setup <<<2,256>>>: block0 = graph CSR build; block1 = weight folding ======
__global__ __launch_bounds__(256) void k_setup(
        const float* __restrict__ c1w, const float* __restrict__ c1b,
        const float* __restrict__ g1, const float* __restrict__ b1,
        const float* __restrict__ c2w, const float* __restrict__ c2b,
        const float* __restrict__ g2, const float* __restrict__ b2,
        const float* __restrict__ c3w, const float* __restrict__ c3b,
        const float* __restrict__ g3, const float* __restrict__ b3,
        const float* __restrict__ w1, const float* __restrict__ w2,
        const float* __restrict__ dw,
        const int* __restrict__ ei, const int* __restrict__ batch,
        float* __restrict__ wf1t, float* __restrict__ bf1,
        unsigned short* __restrict__ wB2, float* __restrict__ bf2c,
        unsigned short* __restrict__ wB3, float* __restrict__ bf3c,
        unsigned short* __restrict__ wt1, unsigned short* __restrict__ wt2,
        float* __restrict__ dwt,
        int* __restrict__ offs, int* __restrict__ count, float* __restrict__ dinv,
        int* __restrict__ csr, int* __restrict__ cnt, float* __restrict__ lacc) {
    __shared__ int cntL[N_];
    __shared__ int offL[N_];
    __shared__ int part[256];
    __shared__ int bcnt[B_];
    int tid = threadIdx.x;
    const float rs = rsqrtf(1.f + EPS_);
    if (blockIdx.x == 0) {
        // ---------- graph ----------
        for (int i = tid; i < N_; i += 256) cntL[i] = 0;
        if (tid < B_) bcnt[tid] = 0;
        if (tid < B_ * 4) lacc[tid] = 0.f;
        __syncthreads();
#pragma unroll
        for (int it = 0; it < E_ / 256; ++it) atomicAdd(&cntL[ei[E_ + tid + 256 * it]], 1);
#pragma unroll
        for (int it = 0; it < N_ / 256; ++it) atomicAdd(&bcnt[batch[tid + 256 * it]], 1);
        __syncthreads();
        {
            int loc[8];
            int s = 0;
            int base = tid * 8;
#pragma unroll
            for (int j = 0; j < 8; ++j) { loc[j] = cntL[base + j]; s += loc[j]; }
            part[tid] = s;
            __syncthreads();
            for (int o = 1; o < 256; o <<= 1) {
                int add = (tid >= o) ? part[tid - o] : 0;
                __syncthreads();
                part[tid] += add;
                __syncthreads();
            }
            int run = part[tid] - s;
#pragma unroll
            for (int j = 0; j < 8; ++j) {
                offL[base + j] = run;
                offs[base + j] = run;
                count[base + j] = loc[j];
                dinv[base + j] = rsqrtf((float)(loc[j] + 1));
                run += loc[j];
            }
            if (tid < B_) cnt[tid] = bcnt[tid];
        }
        __syncthreads();
        for (int i = tid; i < N_; i += 256) cntL[i] = offL[i];  // cursors
        __syncthreads();
#pragma unroll
        for (int it = 0; it < E_ / 256; ++it) {
            int e = tid + 256 * it;
            int d = ei[E_ + e], src = ei[e];
            int p = atomicAdd(&cntL[d], 1);
            csr[p] = src;
        }
    } else {
        // ---------- weights ----------
        for (int i = tid; i < C1_ * K1_; i += 256) {
            int k = i >> 3, c = i & 7;
            wf1t[i] = c1w[c * K1_ + k] * g1[c] * rs;
        }
        if (tid < C1_) bf1[tid] = c1b[tid] * g1[tid] * rs + b1[tid];
        // wB2[g][c2][ph*8+c1]: fused conv2 taps m=4g+ph (0 if m>=18)
        for (int i = tid; i < 5 * C2_ * 32; i += 256) {
            int g = i >> 9, rem = i & 511;
            int c2 = rem >> 5, k32 = rem & 31;
            int ph = k32 >> 3, c1 = k32 & 7;
            int m = 4 * g + ph;
            float s = 0.f;
            if (m < M2_) {
                for (int k = 0; k < K2_; ++k) { int d = m - k; if (d >= 0 && d <= 3) s += c2w[(c2 * C1_ + c1) * K2_ + k]; }
                s *= g2[c2] * rs * 0.25f;
            }
            wB2[i] = f2bf(s);
        }
        if (tid < C2_) bf2c[tid] = c2b[tid] * g2[tid] * rs + b2[tid];
        // wB3[g][c3][mloc*16+c2]: fused conv3 taps m=2g+mloc
        for (int i = tid; i < 5 * C3_ * 32; i += 256) {
            int g = i >> 10, rem = i & 1023;
            int c3 = rem >> 5, j = rem & 31;
            int c2 = j & 15, mloc = j >> 4;
            int m = 2 * g + mloc;
            float s = 0.f;
            for (int k = 0; k < K3_; ++k) { int d = m - k; if (d >= 0 && d <= 3) s += c3w[(c3 * C2_ + c2) * K3_ + k]; }
            wB3[i] = f2bf(s * g3[c3] * rs * 0.25f);
        }
        if (tid < C3_) bf3c[tid] = c3b[tid] * g3[tid] * rs + b3[tid];
        // wt1[d][c] (128x32), wt2[d2][d1] (128x128)
        for (int i = tid; i < C3_ * D_; i += 256) { int d = i >> 5, c = i & 31; wt1[i] = f2bf(w1[c * D_ + d]); }
        for (int i = tid; i < D_ * D_; i += 256) { int d2 = i >> 7, d1 = i & 127; wt2[i] = f2bf(w2[d1 * D_ + d2]); }
        // dwt[(t*128+col)*4+j] = dw[(col*61+t)*4+j]  (coalesced epilogue reads)
        for (int i = tid; i < T2_ * D_ * 4; i += 256) {
            int t = i >> 9, col = (i >> 2) & 127, j = i & 3;
            dwt[i] = dw[((size_t)col * T2_ + t) * 4 + j];
        }
    }
}

// ====== mega-fused conv stack: pe-MLP + conv1 VALU -> conv2 MFMA -> conv3 MFMA ======
__global__ __launch_bounds__(256) void k_conv123(const float* __restrict__ x,
        const float* __restrict__ pos,
        const float* __restrict__ pw1, const float* __restrict__ pb1,
        const float* __restrict__ pw2, const float* __restrict__ pb2,
        const float* __restrict__ wf1t, const float* __restrict__ bf1,
        const unsigned short* __restrict__ wB2g, const float* __restrict__ bf2c,
        const unsigned short* __restrict__ wB3g, const float* __restrict__ bf3c,
        unsigned short* __restrict__ h3) {
    __shared__ __align__(16) float xin[T_ + 32];               // halo 12 + pad
    __shared__ __align__(16) float wl1[C1_ * K1_];
    __shared__ __align__(16) unsigned short xs2[260 * 40];     // 20.8 KB
    __shared__ __align__(16) unsigned short xs3[66 * 72];      // 9.5 KB
    __shared__ float hid[32], pes[32];
    int n = blockIdx.x, tid = threadIdx.x;
    int wid = tid >> 6, lane = tid & 63;
    int lrow = lane & 15, lk = lane >> 4;
    for (int i = tid; i < T_ + 32; i += 256) {
        int gi = i - 12;
        xin[i] = (gi >= 0 && gi < T_) ? x[n * T_ + gi] : 0.f;
    }
    if (tid < C1_ * K1_) wl1[tid] = wf1t[tid];
    if (tid < 32) {
        float p0 = pos[n * 3], p1 = pos[n * 3 + 1], p2 = pos[n * 3 + 2];
        hid[tid] = fmaxf(p0 * pw1[tid] + p1 * pw1[32 + tid] + p2 * pw1[64 + tid] + pb1[tid], 0.f);
    }
    float bl1r[C1_];
#pragma unroll
    for (int c = 0; c < C1_; ++c) bl1r[c] = bf1[c];
    __syncthreads();
    if (tid < 32) {
        float o = pb2[tid];
#pragma unroll
        for (int cc = 0; cc < 32; ++cc) o += hid[cc] * pw2[cc * 32 + tid];
        pes[tid] = o;
    }
    // ---- conv1 (f32 VALU) -> xs2 bf16 fragments ----
#pragma unroll
    for (int it = 0; it < 4; ++it) {
        int t = tid + 256 * it;
        float a[C1_];
#pragma unroll
        for (int c = 0; c < C1_; ++c) a[c] = bl1r[c];
#pragma unroll
        for (int k = 0; k < K1_; ++k) {
            float xv = xin[t + k];
            const f32x4* wp = (const f32x4*)&wl1[k * C1_];
            f32x4 w0 = wp[0], w1v = wp[1];
#pragma unroll
            for (int j = 0; j < 4; ++j) { a[j] += w0[j] * xv; a[4 + j] += w1v[j] * xv; }
        }
        int u = t >> 2, ph = t & 3;
        bf16x8 sv;
#pragma unroll
        for (int c = 0; c < C1_; ++c) sv[c] = (short)f2bf(fmaxf(a[c], 0.f));
        *(bf16x8*)&xs2[u * 40 + ph * 8] = sv;
    }
    __syncthreads();
    // ---- conv2 via MFMA (B from L2), epilogue -> xs3 fragments ----
    {
        bf16x8 bfr[5];
#pragma unroll
        for (int g = 0; g < 5; ++g)
            bfr[g] = *(const bf16x8*)(wB2g + g * 512 + lrow * 32 + lk * 8);
        float bb = bf2c[lrow];
#pragma unroll
        for (int mt = 0; mt < 4; ++mt) {
            int p0 = (wid * 4 + mt) * 16;
            f32x4 c4 = {0.f, 0.f, 0.f, 0.f};
#pragma unroll
            for (int g = 0; g < 5; ++g) {
                bf16x8 af = *(const bf16x8*)&xs2[(p0 + lrow + g) * 40 + lk * 8];
                c4 = __builtin_amdgcn_mfma_f32_16x16x32_bf16(af, bfr[g], c4, 0, 0, 0);
            }
            int urow = (p0 >> 2) + lk;
#pragma unroll
            for (int r = 0; r < 4; ++r)
                xs3[urow * 72 + r * 16 + lrow] = f2bf(fmaxf(c4[r] + bb, 0.f));
        }
    }
    __syncthreads();
    // ---- conv3 via MFMA (B from L2) + bias + relu + pe -> h3 ----
    {
        int t0 = wid * 16;
        f32x4 acc[2];
        acc[0] = f32x4{0.f, 0.f, 0.f, 0.f};
        acc[1] = f32x4{0.f, 0.f, 0.f, 0.f};
        bf16x8 af[5];
#pragma unroll
        for (int g = 0; g < 5; ++g)
            af[g] = *(const bf16x8*)&xs3[(t0 + lrow + (g >> 1)) * 72 + (g & 1) * 32 + lk * 8];
#pragma unroll
        for (int nn = 0; nn < 2; ++nn) {
#pragma unroll
            for (int g = 0; g < 5; ++g) {
                bf16x8 bf = *(const bf16x8*)(wB3g + g * 1024 + (nn * 16 + lrow) * 32 + lk * 8);
                acc[nn] = __builtin_amdgcn_mfma_f32_16x16x32_bf16(af[g], bf, acc[nn], 0, 0, 0);
            }
        }
#pragma unroll
        for (int nn = 0; nn < 2; ++nn) {
            int c3 = nn * 16 + lrow;
            float b3v = bf3c[c3];
            float pev = pes[c3];
#pragma unroll
            for (int r = 0; r < 4; ++r) {
                int t = t0 + lk * 4 + r;
                if (t < T2_)
                    h3[(size_t)n * H3E_ + t * C3_ + c3] = f2bf(fmaxf(acc[nn][r] + b3v, 0.f) + pev);
            }
        }
    }
}

// ====== gather aggregation layer 1 (bf16 in/out, f32 accum, both dinv folded) ======
template <int NG>
__global__ __launch_bounds__(256) void k_agg_bf(const unsigned short* __restrict__ h,
        const int* __restrict__ off, const int* __restrict__ cnt, const int* __restrict__ csr,
        const float* __restrict__ dinv, unsigned short* __restrict__ out) {
    int n = blockIdx.x, tid = threadIdx.x;
    float acc[8];
    float dn = dinv[n];
    const bf16x8* self = (const bf16x8*)(h + (size_t)n * NG * 8);
    if (tid < NG) {
        bf16x8 v = self[tid];
#pragma unroll
        for (int j = 0; j < 8; ++j) acc[j] = dn * bf2f((unsigned short)v[j]);
    }
    int st = off[n], c = cnt[n];
    for (int i = 0; i < c; ++i) {
        int sn = csr[st + i];
        float f = dinv[sn];
        if (tid < NG) {
            bf16x8 v = ((const bf16x8*)(h + (size_t)sn * NG * 8))[tid];
#pragma unroll
            for (int j = 0; j < 8; ++j) acc[j] += f * bf2f((unsigned short)v[j]);
        }
    }
    if (tid < NG) {
        bf16x8 v;
#pragma unroll
        for (int j = 0; j < 8; ++j) v[j] = (short)f2bf(acc[j] * dn);
        ((bf16x8*)(out + (size_t)n * NG * 8))[tid] = v;
    }
}

// ====== FUSED gemm1+agg2: wave = 16-row block x ALL 128 cols (A read once) ======
// agg2[n] = dinv[n] * sum_s dinv[s]*relu(agg1[s]@W1+b1)
__global__ __launch_bounds__(256) void k_agg_gemm1(const unsigned short* __restrict__ agg1,
        const unsigned short* __restrict__ wt1, const float* __restrict__ bias,
        const int* __restrict__ off, const int* __restrict__ cnt, const int* __restrict__ csr,
        const float* __restrict__ dinv, unsigned short* __restrict__ agg2) {
    int n = blockIdx.x, tid = threadIdx.x;
    int wid = tid >> 6, lane = tid & 63;
    int lrow = lane & 15, lk = lane >> 4;
    bf16x8 bfr[8];
    float bv[8];
#pragma unroll
    for (int nn = 0; nn < 8; ++nn) {
        int col = nn * 16 + lrow;
        bfr[nn] = *(const bf16x8*)&wt1[col * 32 + lk * 8];
        bv[nn] = bias[col];
    }
    f32x4 acc[8];
#pragma unroll
    for (int nn = 0; nn < 8; ++nn) acc[nn] = f32x4{0.f, 0.f, 0.f, 0.f};
    int st = off[n], c = cnt[n];
    int arow_off = (wid * 16 + lrow) * 32 + lk * 8;
    for (int i = -1; i < c; ++i) {
        int s = (i < 0) ? n : csr[st + i];
        float f = dinv[s];
        bf16x8 af = *(const bf16x8*)(agg1 + (size_t)s * H3E_ + arow_off);
#pragma unroll
        for (int nn = 0; nn < 8; ++nn) {
            f32x4 t4 = {0.f, 0.f, 0.f, 0.f};
            t4 = __builtin_amdgcn_mfma_f32_16x16x32_bf16(af, bfr[nn], t4, 0, 0, 0);
#pragma unroll
            for (int r = 0; r < 4; ++r)
                acc[nn][r] += f * fmaxf(t4[r] + bv[nn], 0.f);
        }
    }
    float dn = dinv[n];
    unsigned short* orow = agg2 + (size_t)n * HGE_;
#pragma unroll
    for (int r = 0; r < 4; ++r) {
        int t = wid * 16 + lk * 4 + r;
        if (t < T2_) {
#pragma unroll
            for (int nn = 0; nn < 8; ++nn)
                orow[t * D_ + nn * 16 + lrow] = f2bf(acc[nn][r] * dn);
        }
    }
}

// ====== MFMA GEMM K=128 + fused dense projection (wave = 32 rows x all cols) ======
__global__ __launch_bounds__(256) void k_gemm_mfma2f(const unsigned short* __restrict__ A,
        const unsigned short* __restrict__ Bt, const float* __restrict__ bias,
        const float* __restrict__ dwt, const int* __restrict__ batch,
        float* __restrict__ lacc) {
    __shared__ float bacc[B_ * 4];
    int tid = threadIdx.x;
    if (tid < B_ * 4) bacc[tid] = 0.f;
    int blk = blockIdx.x;
    int wid = tid >> 6, lane = tid & 63;
    int row0 = blk * 128 + wid * 32;
    int lrow = lane & 15, lk = lane >> 4;
    f32x4 acc[2][8];
#pragma unroll
    for (int m = 0; m < 2; ++m)
#pragma unroll
        for (int nn = 0; nn < 8; ++nn)
#pragma unroll
            for (int r = 0; r < 4; ++r) acc[m][nn][r] = 0.f;
#pragma unroll
    for (int ks = 0; ks < 4; ++ks) {
        bf16x8 a[2], b[8];
#pragma unroll
        for (int m = 0; m < 2; ++m)
            a[m] = *(const bf16x8*)(A + ((size_t)(row0 + m * 16 + lrow)) * D_ + ks * 32 + lk * 8);
#pragma unroll
        for (int nn = 0; nn < 8; ++nn)
            b[nn] = *(const bf16x8*)(Bt + ((size_t)(nn * 16 + lrow)) * D_ + ks * 32 + lk * 8);
#pragma unroll
        for (int m = 0; m < 2; ++m)
#pragma unroll
            for (int nn = 0; nn < 8; ++nn)
                acc[m][nn] = __builtin_amdgcn_mfma_f32_16x16x32_bf16(a[m], b[nn], acc[m][nn], 0, 0, 0);
    }
    float bvv[8];
#pragma unroll
    for (int nn = 0; nn < 8; ++nn) bvv[nn] = bias[nn * 16 + lrow];
    __syncthreads();   // bacc zero visible
    int cur_b = -1;
    f32x4 sacc = {0.f, 0.f, 0.f, 0.f};
#pragma unroll
    for (int m = 0; m < 2; ++m) {
#pragma unroll
        for (int r = 0; r < 4; ++r) {
            int row = row0 + m * 16 + lk * 4 + r;
            int n = row / T2_;
            int t = row - n * T2_;
            int b = batch[n];
            f32x4 s = {0.f, 0.f, 0.f, 0.f};
#pragma unroll
            for (int nn = 0; nn < 8; ++nn) {
                float v = fmaxf(acc[m][nn][r] + bvv[nn], 0.f);
                f32x4 w = *(const f32x4*)(dwt + ((size_t)t * D_ + nn * 16 + lrow) * 4);
                s += v * w;
            }
            if (b != cur_b) {
                if (cur_b >= 0) {
#pragma unroll
                    for (int j = 0; j < 4; ++j) atomicAdd(&bacc[cur_b * 4 + j], sacc[j]);
                }
                cur_b = b;
                sacc = s;
            } else {
                sacc += s;
            }
        }
    }
    if (cur_b >= 0) {
#pragma unroll
        for (int j = 0; j < 4; ++j) atomicAdd(&bacc[cur_b * 4 + j], sacc[j]);
    }
    __syncthreads();
    if (tid < B_ * 4) {
        float v = bacc[tid];
        if (v != 0.f) atomicAdd(&lacc[tid], v);
    }
}

// ============== tiny final: /cnt, +db, log_softmax ==============
__global__ void k_final2(const float* __restrict__ acc, const int* __restrict__ cnt,
                         const float* __restrict__ db, float* __restrict__ out) {
    int b = threadIdx.x;
    if (b < B_) {
        float inv = 1.f / fmaxf((float)cnt[b], 1.f);
        float l[4];
#pragma unroll
        for (int j = 0; j < 4; ++j) l[j] = acc[b * 4 + j] * inv + db[j];
        float m = fmaxf(fmaxf(l[0], l[1]), fmaxf(l[2], l[3]));
        float s = expf(l[0] - m) + expf(l[1] - m) + expf(l[2] - m) + expf(l[3] - m);
        float ls = m + logf(s);
#pragma unroll
        for (int j = 0; j < 4; ++j) out[b * 4 + j] = l[j] - ls;
    }
}

// ======================= launch =======================
extern "C" void kernel_launch(void* const* d_in, const int* in_sizes, int n_in,
                              void* d_out, int out_size, void* d_ws, size_t ws_size,
                              hipStream_t stream) {
    const float* x       = (const float*)d_in[0];
    const float* pos     = (const float*)d_in[1];
    const float* conv1_w = (const float*)d_in[2];
    const float* conv1_b = (const float*)d_in[3];
    const float* bn1_g   = (const float*)d_in[4];
    const float* bn1_b   = (const float*)d_in[5];
    const float* conv2_w = (const float*)d_in[6];
    const float* conv2_b = (const float*)d_in[7];
    const float* bn2_g   = (const float*)d_in[8];
    const float* bn2_b   = (const float*)d_in[9];
    const float* conv3_w = (const float*)d_in[10];
    const float* conv3_b = (const float*)d_in[11];
    const float* bn3_g   = (const float*)d_in[12];
    const float* bn3_b   = (const float*)d_in[13];
    const float* pos_w1  = (const float*)d_in[14];
    const float* pos_b1  = (const float*)d_in[15];
    const float* pos_w2  = (const float*)d_in[16];
    const float* pos_b2  = (const float*)d_in[17];
    const float* gcn1_w  = (const float*)d_in[18];
    const float* gcn1_b  = (const float*)d_in[19];
    const float* gcn2_w  = (const float*)d_in[20];
    const float* gcn2_b  = (const float*)d_in[21];
    const float* dense_w = (const float*)d_in[22];
    const float* dense_b = (const float*)d_in[23];
    const int*   eidx    = (const int*)d_in[24];
    const int*   batch   = (const int*)d_in[25];
    float* out = (float*)d_out;
    char* ws = (char*)d_ws;

    size_t off = 0;
    auto alloc = [&](size_t bytes) { size_t o = off; off += (bytes + 255) & ~(size_t)255; return o; };
    size_t o_h3     = alloc((size_t)N_ * H3E_ * 2);              // 8 MB bf16
    size_t o_agg1   = alloc(((size_t)N_ * H3E_ + 2048) * 2);     // 8 MB bf16 (+slack for row-64 overreads)
    size_t o_agg2   = alloc((size_t)N_ * HGE_ * 2);              // 32 MB bf16
    size_t o_lacc   = alloc((size_t)B_ * 4 * 4);
    size_t o_count  = alloc((size_t)N_ * 4);
    size_t o_off    = alloc((size_t)N_ * 4);
    size_t o_dinv   = alloc((size_t)N_ * 4);
    size_t o_csr    = alloc((size_t)E_ * 4);
    size_t o_cnt    = alloc((size_t)B_ * 4);
    size_t o_wf1t   = alloc((size_t)C1_ * K1_ * 4);
    size_t o_bf1    = alloc((size_t)C1_ * 4);
    size_t o_wB2    = alloc((size_t)5 * C2_ * 32 * 2);
    size_t o_bf2c   = alloc((size_t)C2_ * 4);
    size_t o_wB3    = alloc((size_t)5 * C3_ * 32 * 2);
    size_t o_bf3c   = alloc((size_t)C3_ * 4);
    size_t o_wt1    = alloc((size_t)C3_ * D_ * 2);
    size_t o_wt2    = alloc((size_t)D_ * D_ * 2);
    size_t o_dwt    = alloc((size_t)T2_ * D_ * 4 * 4);

    unsigned short* h3   = (unsigned short*)(ws + o_h3);
    unsigned short* agg1 = (unsigned short*)(ws + o_agg1);
    unsigned short* agg2 = (unsigned short*)(ws + o_agg2);
    float* lacc   = (float*)(ws + o_lacc);
    int*   count  = (int*)(ws + o_count);
    int*   offs   = (int*)(ws + o_off);
    float* dinv   = (float*)(ws + o_dinv);
    int*   csr    = (int*)(ws + o_csr);
    int*   cnt    = (int*)(ws + o_cnt);
    float* wf1t   = (float*)(ws + o_wf1t);
    float* bf1    = (float*)(ws + o_bf1);
    unsigned short* wB2 = (unsigned short*)(ws + o_wB2);
    float* bf2c   = (float*)(ws + o_bf2c);
    unsigned short* wB3 = (unsigned short*)(ws + o_wB3);
    float* bf3c   = (float*)(ws + o_bf3c);
    unsigned short* wt1 = (unsigned short*)(ws + o_wt1);
    unsigned short* wt2 = (unsigned short*)(ws + o_wt2);
    float* dwt    = (float*)(ws + o_dwt);

    k_setup<<<2, 256, 0, stream>>>(conv1_w, conv1_b, bn1_g, bn1_b,
                                   conv2_w, conv2_b, bn2_g, bn2_b,
                                   conv3_w, conv3_b, bn3_g, bn3_b,
                                   gcn1_w, gcn2_w, dense_w, eidx, batch,
                                   wf1t, bf1, wB2, bf2c, wB3, bf3c, wt1, wt2, dwt,
                                   offs, count, dinv, csr, cnt, lacc);
    k_conv123<<<N_, 256, 0, stream>>>(x, pos, pos_w1, pos_b1, pos_w2, pos_b2,
                                      wf1t, bf1, wB2, bf2c, wB3, bf3c, h3);
    k_agg_bf<H3E_ / 8><<<N_, 256, 0, stream>>>(h3, offs, count, csr, dinv, agg1);
    k_agg_gemm1<<<N_, 256, 0, stream>>>(agg1, wt1, gcn1_b, offs, count, csr, dinv, agg2);
    k_gemm_mfma2f<<<M_ / 128, 256, 0, stream>>>(agg2, wt2, gcn2_b, dwt, batch, lacc);
    k_final2<<<1, 64, 0, stream>>>(lacc, cnt, dense_b, out);
}

// Round 7
// 240.194 us; speedup vs baseline: 1.5178x; 1.1063x over previous
//
#include <hip/hip_runtime.h>
#include <math.h>

// ---- problem constants ----
constexpr int N_  = 2048;
constexpr int T_  = 1024;
constexpr int E_  = 16384;
constexpr int B_  = 32;
constexpr int C1_ = 8,  C2_ = 16, C3_ = 32;
constexpr int K1_ = 25, K2_ = 15, K3_ = 7;
constexpr int T2_ = 61;           // conv3+pool output length
constexpr int D_  = 128;
constexpr float EPS_ = 1e-5f;
constexpr int M2_ = K2_ + 3;      // 18 fused taps (conv2 ⊗ pool4)
constexpr int H3E_ = T2_ * C3_;   // 1952 elems/node after conv stack
constexpr int HGE_ = T2_ * D_;    // 7808 elems/node in GCN space
constexpr int M_   = N_ * T2_;    // 124928 flattened GEMM rows (= 976*128)
constexpr int FILLB_ = E_ / 256;  // 64 fill blocks

typedef __attribute__((ext_vector_type(4))) float f32x4;
typedef __attribute__((ext_vector_type(8))) short bf16x8;

__device__ __forceinline__ unsigned short f2bf(float f) {
    unsigned int u = __float_as_uint(f);
    unsigned int r = (u + 0x7fffu + ((u >> 16) & 1u)) >> 16;
    return (unsigned short)r;
}
__device__ __forceinline__ float bf2f(unsigned short s) {
    return __uint_as_float((unsigned int)s << 16);
}

// ====== k_init <<<12,256>>>: b0 = degree/batch histograms; b1-3 = weight fold;
// ======                      b4-11 = dense_w transpose (coalesced reads) ======
__global__ __launch_bounds__(256) void k_init(
        const float* __restrict__ c1w, const float* __restrict__ c1b,
        const float* __restrict__ g1, const float* __restrict__ b1,
        const float* __restrict__ c2w, const float* __restrict__ c2b,
        const float* __restrict__ g2, const float* __restrict__ b2,
        const float* __restrict__ c3w, const float* __restrict__ c3b,
        const float* __restrict__ g3, const float* __restrict__ b3,
        const float* __restrict__ w1, const float* __restrict__ w2,
        const float* __restrict__ dw,
        const int* __restrict__ ei, const int* __restrict__ batch,
        float* __restrict__ wf1t, float* __restrict__ bf1,
        unsigned short* __restrict__ wB2, float* __restrict__ bf2c,
        unsigned short* __restrict__ wB3, float* __restrict__ bf3c,
        unsigned short* __restrict__ wt1, unsigned short* __restrict__ wt2,
        float* __restrict__ dwt,
        int* __restrict__ count, float* __restrict__ dinv,
        int* __restrict__ cnt, float* __restrict__ lacc) {
    __shared__ int cntL[N_];
    __shared__ int bcnt[B_];
    int bid = blockIdx.x, tid = threadIdx.x;
    const float rs = rsqrtf(1.f + EPS_);
    if (bid == 0) {
        // ---- degree + batch histograms in LDS ----
        for (int i = tid; i < N_; i += 256) cntL[i] = 0;
        if (tid < B_) bcnt[tid] = 0;
        if (tid < B_ * 4) lacc[tid] = 0.f;
        __syncthreads();
#pragma unroll
        for (int it = 0; it < E_ / 256; ++it) atomicAdd(&cntL[ei[E_ + tid + 256 * it]], 1);
#pragma unroll
        for (int it = 0; it < N_ / 256; ++it) atomicAdd(&bcnt[batch[tid + 256 * it]], 1);
        __syncthreads();
        for (int i = tid; i < N_; i += 256) {
            int c = cntL[i];
            count[i] = c;
            dinv[i] = rsqrtf((float)(c + 1));
        }
        if (tid < B_) cnt[tid] = bcnt[tid];
    } else if (bid == 1) {
        // ---- conv1 weights + biases + conv2 B-operand ----
        for (int i = tid; i < C1_ * K1_; i += 256) {
            int k = i >> 3, c = i & 7;
            wf1t[i] = c1w[c * K1_ + k] * g1[c] * rs;
        }
        if (tid < C1_) bf1[tid] = c1b[tid] * g1[tid] * rs + b1[tid];
        if (tid >= 32 && tid < 48) { int c = tid - 32; bf2c[c] = c2b[c] * g2[c] * rs + b2[c]; }
        if (tid >= 64 && tid < 96) { int c = tid - 64; bf3c[c] = c3b[c] * g3[c] * rs + b3[c]; }
        // wB2[g][c2][ph*8+c1]: fused conv2 taps m=4g+ph (0 if m>=18)
        for (int i = tid; i < 5 * C2_ * 32; i += 256) {
            int g = i >> 9, rem = i & 511;
            int c2 = rem >> 5, k32 = rem & 31;
            int ph = k32 >> 3, c1 = k32 & 7;
            int m = 4 * g + ph;
            float s = 0.f;
            if (m < M2_) {
                for (int k = 0; k < K2_; ++k) { int d = m - k; if (d >= 0 && d <= 3) s += c2w[(c2 * C1_ + c1) * K2_ + k]; }
                s *= g2[c2] * rs * 0.25f;
            }
            wB2[i] = f2bf(s);
        }
    } else if (bid == 2) {
        // ---- conv3 B-operand + gcn1 weights ----
        for (int i = tid; i < 5 * C3_ * 32; i += 256) {
            int g = i >> 10, rem = i & 1023;
            int c3 = rem >> 5, j = rem & 31;
            int c2 = j & 15, mloc = j >> 4;
            int m = 2 * g + mloc;
            float s = 0.f;
            for (int k = 0; k < K3_; ++k) { int d = m - k; if (d >= 0 && d <= 3) s += c3w[(c3 * C2_ + c2) * K3_ + k]; }
            wB3[i] = f2bf(s * g3[c3] * rs * 0.25f);
        }
        for (int i = tid; i < C3_ * D_; i += 256) { int d = i >> 5, c = i & 31; wt1[i] = f2bf(w1[c * D_ + d]); }
    } else if (bid == 3) {
        // ---- gcn2 weights (128x128 transpose) ----
        for (int i = tid; i < D_ * D_; i += 256) { int d2 = i >> 7, d1 = i & 127; wt2[i] = f2bf(w2[d1 * D_ + d2]); }
    } else {
        // ---- dense_w transpose: coalesced READS of dw, scattered writes ----
        int seg = bid - 4;                       // 0..7
        int start = seg * (T2_ * D_ * 4 / 8);    // 3904 each
        for (int q = start + tid; q < start + T2_ * D_ * 4 / 8; q += 256) {
            int col = q / (T2_ * 4);
            int r = q - col * (T2_ * 4);
            int t = r >> 2, j = r & 3;
            dwt[(t * D_ + col) * 4 + j] = dw[q];
        }
    }
}

// ====== k_scan <<<1,256>>>: exclusive prefix over count -> offs, cur ======
__global__ __launch_bounds__(256) void k_scan(const int* __restrict__ count,
        int* __restrict__ offs, int* __restrict__ cur) {
    __shared__ int part[256];
    int tid = threadIdx.x;
    int loc[8];
    int s = 0;
    int base = tid * 8;
#pragma unroll
    for (int j = 0; j < 8; ++j) { loc[j] = count[base + j]; s += loc[j]; }
    part[tid] = s;
    __syncthreads();
    for (int o = 1; o < 256; o <<= 1) {
        int add = (tid >= o) ? part[tid - o] : 0;
        __syncthreads();
        part[tid] += add;
        __syncthreads();
    }
    int run = part[tid] - s;
#pragma unroll
    for (int j = 0; j < 8; ++j) {
        offs[base + j] = run;
        cur[base + j] = run;
        run += loc[j];
    }
}

// ====== k_fillconv <<<64+2048>>>: blocks 0-63 CSR fill; blocks 64+ conv stack ======
// conv: pe-MLP + conv1 VALU -> conv2 MFMA -> conv3 MFMA  (unchanged structure)
__global__ __launch_bounds__(256) void k_fillconv(const float* __restrict__ x,
        const float* __restrict__ pos,
        const float* __restrict__ pw1, const float* __restrict__ pb1,
        const float* __restrict__ pw2, const float* __restrict__ pb2,
        const float* __restrict__ wf1t, const float* __restrict__ bf1,
        const unsigned short* __restrict__ wB2g, const float* __restrict__ bf2c,
        const unsigned short* __restrict__ wB3g, const float* __restrict__ bf3c,
        const int* __restrict__ ei, int* __restrict__ cur, int* __restrict__ csr,
        unsigned short* __restrict__ h3) {
    __shared__ __align__(16) float xin[T_ + 32];               // halo 12 + pad
    __shared__ __align__(16) float wl1[C1_ * K1_];
    __shared__ __align__(16) unsigned short xs2[260 * 40];     // 20.8 KB
    __shared__ __align__(16) unsigned short xs3[66 * 72];      // 9.5 KB
    __shared__ float hid[32], pes[32];
    int bid = blockIdx.x, tid = threadIdx.x;
    if (bid < FILLB_) {
        // ---- CSR fill via global-atomic cursors ----
        int e = bid * 256 + tid;
        int d = ei[E_ + e], src = ei[e];
        int p = atomicAdd(&cur[d], 1);
        csr[p] = src;
        return;
    }
    int n = bid - FILLB_;
    int wid = tid >> 6, lane = tid & 63;
    int lrow = lane & 15, lk = lane >> 4;
    for (int i = tid; i < T_ + 32; i += 256) {
        int gi = i - 12;
        xin[i] = (gi >= 0 && gi < T_) ? x[n * T_ + gi] : 0.f;
    }
    if (tid < C1_ * K1_) wl1[tid] = wf1t[tid];
    if (tid < 32) {
        float p0 = pos[n * 3], p1 = pos[n * 3 + 1], p2 = pos[n * 3 + 2];
        hid[tid] = fmaxf(p0 * pw1[tid] + p1 * pw1[32 + tid] + p2 * pw1[64 + tid] + pb1[tid], 0.f);
    }
    float bl1r[C1_];
#pragma unroll
    for (int c = 0; c < C1_; ++c) bl1r[c] = bf1[c];
    __syncthreads();
    if (tid < 32) {
        float o = pb2[tid];
#pragma unroll
        for (int cc = 0; cc < 32; ++cc) o += hid[cc] * pw2[cc * 32 + tid];
        pes[tid] = o;
    }
    // ---- conv1 (f32 VALU) -> xs2 bf16 fragments ----
#pragma unroll
    for (int it = 0; it < 4; ++it) {
        int t = tid + 256 * it;
        float a[C1_];
#pragma unroll
        for (int c = 0; c < C1_; ++c) a[c] = bl1r[c];
#pragma unroll
        for (int k = 0; k < K1_; ++k) {
            float xv = xin[t + k];
            const f32x4* wp = (const f32x4*)&wl1[k * C1_];
            f32x4 w0 = wp[0], w1v = wp[1];
#pragma unroll
            for (int j = 0; j < 4; ++j) { a[j] += w0[j] * xv; a[4 + j] += w1v[j] * xv; }
        }
        int u = t >> 2, ph = t & 3;
        bf16x8 sv;
#pragma unroll
        for (int c = 0; c < C1_; ++c) sv[c] = (short)f2bf(fmaxf(a[c], 0.f));
        *(bf16x8*)&xs2[u * 40 + ph * 8] = sv;
    }
    __syncthreads();
    // ---- conv2 via MFMA (B from L2), epilogue -> xs3 fragments ----
    {
        bf16x8 bfr[5];
#pragma unroll
        for (int g = 0; g < 5; ++g)
            bfr[g] = *(const bf16x8*)(wB2g + g * 512 + lrow * 32 + lk * 8);
        float bb = bf2c[lrow];
#pragma unroll
        for (int mt = 0; mt < 4; ++mt) {
            int p0 = (wid * 4 + mt) * 16;
            f32x4 c4 = {0.f, 0.f, 0.f, 0.f};
#pragma unroll
            for (int g = 0; g < 5; ++g) {
                bf16x8 af = *(const bf16x8*)&xs2[(p0 + lrow + g) * 40 + lk * 8];
                c4 = __builtin_amdgcn_mfma_f32_16x16x32_bf16(af, bfr[g], c4, 0, 0, 0);
            }
            int urow = (p0 >> 2) + lk;
#pragma unroll
            for (int r = 0; r < 4; ++r)
                xs3[urow * 72 + r * 16 + lrow] = f2bf(fmaxf(c4[r] + bb, 0.f));
        }
    }
    __syncthreads();
    // ---- conv3 via MFMA (B from L2) + bias + relu + pe -> h3 ----
    {
        int t0 = wid * 16;
        f32x4 acc[2];
        acc[0] = f32x4{0.f, 0.f, 0.f, 0.f};
        acc[1] = f32x4{0.f, 0.f, 0.f, 0.f};
        bf16x8 af[5];
#pragma unroll
        for (int g = 0; g < 5; ++g)
            af[g] = *(const bf16x8*)&xs3[(t0 + lrow + (g >> 1)) * 72 + (g & 1) * 32 + lk * 8];
#pragma unroll
        for (int nn = 0; nn < 2; ++nn) {
#pragma unroll
            for (int g = 0; g < 5; ++g) {
                bf16x8 bf = *(const bf16x8*)(wB3g + g * 1024 + (nn * 16 + lrow) * 32 + lk * 8);
                acc[nn] = __builtin_amdgcn_mfma_f32_16x16x32_bf16(af[g], bf, acc[nn], 0, 0, 0);
            }
        }
#pragma unroll
        for (int nn = 0; nn < 2; ++nn) {
            int c3 = nn * 16 + lrow;
            float b3v = bf3c[c3];
            float pev = pes[c3];
#pragma unroll
            for (int r = 0; r < 4; ++r) {
                int t = t0 + lk * 4 + r;
                if (t < T2_)
                    h3[(size_t)n * H3E_ + t * C3_ + c3] = f2bf(fmaxf(acc[nn][r] + b3v, 0.f) + pev);
            }
        }
    }
}

// ====== gather aggregation layer 1 (bf16 in/out, f32 accum, both dinv folded) ======
template <int NG>
__global__ __launch_bounds__(256) void k_agg_bf(const unsigned short* __restrict__ h,
        const int* __restrict__ off, const int* __restrict__ cnt, const int* __restrict__ csr,
        const float* __restrict__ dinv, unsigned short* __restrict__ out) {
    int n = blockIdx.x, tid = threadIdx.x;
    float acc[8];
    float dn = dinv[n];
    const bf16x8* self = (const bf16x8*)(h + (size_t)n * NG * 8);
    if (tid < NG) {
        bf16x8 v = self[tid];
#pragma unroll
        for (int j = 0; j < 8; ++j) acc[j] = dn * bf2f((unsigned short)v[j]);
    }
    int st = off[n], c = cnt[n];
    for (int i = 0; i < c; ++i) {
        int sn = csr[st + i];
        float f = dinv[sn];
        if (tid < NG) {
            bf16x8 v = ((const bf16x8*)(h + (size_t)sn * NG * 8))[tid];
#pragma unroll
            for (int j = 0; j < 8; ++j) acc[j] += f * bf2f((unsigned short)v[j]);
        }
    }
    if (tid < NG) {
        bf16x8 v;
#pragma unroll
        for (int j = 0; j < 8; ++j) v[j] = (short)f2bf(acc[j] * dn);
        ((bf16x8*)(out + (size_t)n * NG * 8))[tid] = v;
    }
}

// ====== FUSED gemm1+agg2: wave = 16-row block x ALL 128 cols (A read once) ======
__global__ __launch_bounds__(256) void k_agg_gemm1(const unsigned short* __restrict__ agg1,
        const unsigned short* __restrict__ wt1, const float* __restrict__ bias,
        const int* __restrict__ off, const int* __restrict__ cnt, const int* __restrict__ csr,
        const float* __restrict__ dinv, unsigned short* __restrict__ agg2) {
    int n = blockIdx.x, tid = threadIdx.x;
    int wid = tid >> 6, lane = tid & 63;
    int lrow = lane & 15, lk = lane >> 4;
    bf16x8 bfr[8];
    float bv[8];
#pragma unroll
    for (int nn = 0; nn < 8; ++nn) {
        int col = nn * 16 + lrow;
        bfr[nn] = *(const bf16x8*)&wt1[col * 32 + lk * 8];
        bv[nn] = bias[col];
    }
    f32x4 acc[8];
#pragma unroll
    for (int nn = 0; nn < 8; ++nn) acc[nn] = f32x4{0.f, 0.f, 0.f, 0.f};
    int st = off[n], c = cnt[n];
    int arow_off = (wid * 16 + lrow) * 32 + lk * 8;
    for (int i = -1; i < c; ++i) {
        int s = (i < 0) ? n : csr[st + i];
        float f = dinv[s];
        bf16x8 af = *(const bf16x8*)(agg1 + (size_t)s * H3E_ + arow_off);
#pragma unroll
        for (int nn = 0; nn < 8; ++nn) {
            f32x4 t4 = {0.f, 0.f, 0.f, 0.f};
            t4 = __builtin_amdgcn_mfma_f32_16x16x32_bf16(af, bfr[nn], t4, 0, 0, 0);
#pragma unroll
            for (int r = 0; r < 4; ++r)
                acc[nn][r] += f * fmaxf(t4[r] + bv[nn], 0.f);
        }
    }
    float dn = dinv[n];
    unsigned short* orow = agg2 + (size_t)n * HGE_;
#pragma unroll
    for (int r = 0; r < 4; ++r) {
        int t = wid * 16 + lk * 4 + r;
        if (t < T2_) {
#pragma unroll
            for (int nn = 0; nn < 8; ++nn)
                orow[t * D_ + nn * 16 + lrow] = f2bf(acc[nn][r] * dn);
        }
    }
}

// ====== MFMA GEMM K=128 + fused dense projection (wave = 32 rows x all cols) ======
__global__ __launch_bounds__(256) void k_gemm_mfma2f(const unsigned short* __restrict__ A,
        const unsigned short* __restrict__ Bt, const float* __restrict__ bias,
        const float* __restrict__ dwt, const int* __restrict__ batch,
        float* __restrict__ lacc) {
    __shared__ float bacc[B_ * 4];
    int tid = threadIdx.x;
    if (tid < B_ * 4) bacc[tid] = 0.f;
    int blk = blockIdx.x;
    int wid = tid >> 6, lane = tid & 63;
    int row0 = blk * 128 + wid * 32;
    int lrow = lane & 15, lk = lane >> 4;
    f32x4 acc[2][8];
#pragma unroll
    for (int m = 0; m < 2; ++m)
#pragma unroll
        for (int nn = 0; nn < 8; ++nn)
#pragma unroll
            for (int r = 0; r < 4; ++r) acc[m][nn][r] = 0.f;
#pragma unroll
    for (int ks = 0; ks < 4; ++ks) {
        bf16x8 a[2], b[8];
#pragma unroll
        for (int m = 0; m < 2; ++m)
            a[m] = *(const bf16x8*)(A + ((size_t)(row0 + m * 16 + lrow)) * D_ + ks * 32 + lk * 8);
#pragma unroll
        for (int nn = 0; nn < 8; ++nn)
            b[nn] = *(const bf16x8*)(Bt + ((size_t)(nn * 16 + lrow)) * D_ + ks * 32 + lk * 8);
#pragma unroll
        for (int m = 0; m < 2; ++m)
#pragma unroll
            for (int nn = 0; nn < 8; ++nn)
                acc[m][nn] = __builtin_amdgcn_mfma_f32_16x16x32_bf16(a[m], b[nn], acc[m][nn], 0, 0, 0);
    }
    float bvv[8];
#pragma unroll
    for (int nn = 0; nn < 8; ++nn) bvv[nn] = bias[nn * 16 + lrow];
    __syncthreads();   // bacc zero visible
    int cur_b = -1;
    f32x4 sacc = {0.f, 0.f, 0.f, 0.f};
#pragma unroll
    for (int m = 0; m < 2; ++m) {
#pragma unroll
        for (int r = 0; r < 4; ++r) {
            int row = row0 + m * 16 + lk * 4 + r;
            int n = row / T2_;
            int t = row - n * T2_;
            int b = batch[n];
            f32x4 s = {0.f, 0.f, 0.f, 0.f};
#pragma unroll
            for (int nn = 0; nn < 8; ++nn) {
                float v = fmaxf(acc[m][nn][r] + bvv[nn], 0.f);
                f32x4 w = *(const f32x4*)(dwt + ((size_t)t * D_ + nn * 16 + lrow) * 4);
                s += v * w;
            }
            if (b != cur_b) {
                if (cur_b >= 0) {
#pragma unroll
                    for (int j = 0; j < 4; ++j) atomicAdd(&bacc[cur_b * 4 + j], sacc[j]);
                }
                cur_b = b;
                sacc = s;
            } else {
                sacc += s;
            }
        }
    }
    if (cur_b >= 0) {
#pragma unroll
        for (int j = 0; j < 4; ++j) atomicAdd(&bacc[cur_b * 4 + j], sacc[j]);
    }
    __syncthreads();
    if (tid < B_ * 4) {
        float v = bacc[tid];
        if (v != 0.f) atomicAdd(&lacc[tid], v);
    }
}

// ============== tiny final: /cnt, +db, log_softmax ==============
__global__ void k_final2(const float* __restrict__ acc, const int* __restrict__ cnt,
                         const float* __restrict__ db, float* __restrict__ out) {
    int b = threadIdx.x;
    if (b < B_) {
        float inv = 1.f / fmaxf((float)cnt[b], 1.f);
        float l[4];
#pragma unroll
        for (int j = 0; j < 4; ++j) l[j] = acc[b * 4 + j] * inv + db[j];
        float m = fmaxf(fmaxf(l[0], l[1]), fmaxf(l[2], l[3]));
        float s = expf(l[0] - m) + expf(l[1] - m) + expf(l[2] - m) + expf(l[3] - m);
        float ls = m + logf(s);
#pragma unroll
        for (int j = 0; j < 4; ++j) out[b * 4 + j] = l[j] - ls;
    }
}

// ======================= launch =======================
extern "C" void kernel_launch(void* const* d_in, const int* in_sizes, int n_in,
                              void* d_out, int out_size, void* d_ws, size_t ws_size,
                              hipStream_t stream) {
    const float* x       = (const float*)d_in[0];
    const float* pos     = (const float*)d_in[1];
    const float* conv1_w = (const float*)d_in[2];
    const float* conv1_b = (const float*)d_in[3];
    const float* bn1_g   = (const float*)d_in[4];
    const float* bn1_b   = (const float*)d_in[5];
    const float* conv2_w = (const float*)d_in[6];
    const float* conv2_b = (const float*)d_in[7];
    const float* bn2_g   = (const float*)d_in[8];
    const float* bn2_b   = (const float*)d_in[9];
    const float* conv3_w = (const float*)d_in[10];
    const float* conv3_b = (const float*)d_in[11];
    const float* bn3_g   = (const float*)d_in[12];
    const float* bn3_b   = (const float*)d_in[13];
    const float* pos_w1  = (const float*)d_in[14];
    const float* pos_b1  = (const float*)d_in[15];
    const float* pos_w2  = (const float*)d_in[16];
    const float* pos_b2  = (const float*)d_in[17];
    const float* gcn1_w  = (const float*)d_in[18];
    const float* gcn1_b  = (const float*)d_in[19];
    const float* gcn2_w  = (const float*)d_in[20];
    const float* gcn2_b  = (const float*)d_in[21];
    const float* dense_w = (const float*)d_in[22];
    const float* dense_b = (const float*)d_in[23];
    const int*   eidx    = (const int*)d_in[24];
    const int*   batch   = (const int*)d_in[25];
    float* out = (float*)d_out;
    char* ws = (char*)d_ws;

    size_t off = 0;
    auto alloc = [&](size_t bytes) { size_t o = off; off += (bytes + 255) & ~(size_t)255; return o; };
    size_t o_h3     = alloc((size_t)N_ * H3E_ * 2);              // 8 MB bf16
    size_t o_agg1   = alloc(((size_t)N_ * H3E_ + 2048) * 2);     // 8 MB bf16 (+slack for row-64 overreads)
    size_t o_agg2   = alloc((size_t)N_ * HGE_ * 2);              // 32 MB bf16
    size_t o_lacc   = alloc((size_t)B_ * 4 * 4);
    size_t o_count  = alloc((size_t)N_ * 4);
    size_t o_off    = alloc((size_t)N_ * 4);
    size_t o_cur    = alloc((size_t)N_ * 4);
    size_t o_dinv   = alloc((size_t)N_ * 4);
    size_t o_csr    = alloc((size_t)E_ * 4);
    size_t o_cnt    = alloc((size_t)B_ * 4);
    size_t o_wf1t   = alloc((size_t)C1_ * K1_ * 4);
    size_t o_bf1    = alloc((size_t)C1_ * 4);
    size_t o_wB2    = alloc((size_t)5 * C2_ * 32 * 2);
    size_t o_bf2c   = alloc((size_t)C2_ * 4);
    size_t o_wB3    = alloc((size_t)5 * C3_ * 32 * 2);
    size_t o_bf3c   = alloc((size_t)C3_ * 4);
    size_t o_wt1    = alloc((size_t)C3_ * D_ * 2);
    size_t o_wt2    = alloc((size_t)D_ * D_ * 2);
    size_t o_dwt    = alloc((size_t)T2_ * D_ * 4 * 4);

    unsigned short* h3   = (unsigned short*)(ws + o_h3);
    unsigned short* agg1 = (unsigned short*)(ws + o_agg1);
    unsigned short* agg2 = (unsigned short*)(ws + o_agg2);
    float* lacc   = (float*)(ws + o_lacc);
    int*   count  = (int*)(ws + o_count);
    int*   offs   = (int*)(ws + o_off);
    int*   cur    = (int*)(ws + o_cur);
    float* dinv   = (float*)(ws + o_dinv);
    int*   csr    = (int*)(ws + o_csr);
    int*   cnt    = (int*)(ws + o_cnt);
    float* wf1t   = (float*)(ws + o_wf1t);
    float* bf1    = (float*)(ws + o_bf1);
    unsigned short* wB2 = (unsigned short*)(ws + o_wB2);
    float* bf2c   = (float*)(ws + o_bf2c);
    unsigned short* wB3 = (unsigned short*)(ws + o_wB3);
    float* bf3c   = (float*)(ws + o_bf3c);
    unsigned short* wt1 = (unsigned short*)(ws + o_wt1);
    unsigned short* wt2 = (unsigned short*)(ws + o_wt2);
    float* dwt    = (float*)(ws + o_dwt);

    k_init<<<12, 256, 0, stream>>>(conv1_w, conv1_b, bn1_g, bn1_b,
                                   conv2_w, conv2_b, bn2_g, bn2_b,
                                   conv3_w, conv3_b, bn3_g, bn3_b,
                                   gcn1_w, gcn2_w, dense_w, eidx, batch,
                                   wf1t, bf1, wB2, bf2c, wB3, bf3c, wt1, wt2, dwt,
                                   count, dinv, cnt, lacc);
    k_scan<<<1, 256, 0, stream>>>(count, offs, cur);
    k_fillconv<<<FILLB_ + N_, 256, 0, stream>>>(x, pos, pos_w1, pos_b1, pos_w2, pos_b2,
                                                wf1t, bf1, wB2, bf2c, wB3, bf3c,
                                                eidx, cur, csr, h3);
    k_agg_bf<H3E_ / 8><<<N_, 256, 0, stream>>>(h3, offs, count, csr, dinv, agg1);
    k_agg_gemm1<<<N_, 256, 0, stream>>>(agg1, wt1, gcn1_b, offs, count, csr, dinv, agg2);
    k_gemm_mfma2f<<<M_ / 128, 256, 0, stream>>>(agg2, wt2, gcn2_b, dwt, batch, lacc);
    k_final2<<<1, 64, 0, stream>>>(lacc, cnt, dense_b, out);
}

// Round 8
// 236.631 us; speedup vs baseline: 1.5407x; 1.0151x over previous
//
#include <hip/hip_runtime.h>
#include <math.h>

// ---- problem constants ----
constexpr int N_  = 2048;
constexpr int T_  = 1024;
constexpr int E_  = 16384;
constexpr int B_  = 32;
constexpr int C1_ = 8,  C2_ = 16, C3_ = 32;
constexpr int K1_ = 25, K2_ = 15, K3_ = 7;
constexpr int T2_ = 61;           // conv3+pool output length
constexpr int D_  = 128;
constexpr float EPS_ = 1e-5f;
constexpr int M2_ = K2_ + 3;      // 18 fused taps (conv2 ⊗ pool4)
constexpr int H3E_ = T2_ * C3_;   // 1952 elems/node after conv stack
constexpr int HGE_ = T2_ * D_;    // 7808 elems/node in GCN space
constexpr int FILLB_ = E_ / 256;  // 64 fill blocks

typedef __attribute__((ext_vector_type(4))) float f32x4;
typedef __attribute__((ext_vector_type(8))) short bf16x8;

__device__ __forceinline__ unsigned short f2bf(float f) {
    unsigned int u = __float_as_uint(f);
    unsigned int r = (u + 0x7fffu + ((u >> 16) & 1u)) >> 16;
    return (unsigned short)r;
}
__device__ __forceinline__ float bf2f(unsigned short s) {
    return __uint_as_float((unsigned int)s << 16);
}

// ====== k_init <<<12,256>>>: b0 = histograms + scan; b1-3 = weight fold;
// ======                      b4-11 = dense_w transpose (coalesced reads) ======
__global__ __launch_bounds__(256) void k_init(
        const float* __restrict__ c1w, const float* __restrict__ c1b,
        const float* __restrict__ g1, const float* __restrict__ b1,
        const float* __restrict__ c2w, const float* __restrict__ c2b,
        const float* __restrict__ g2, const float* __restrict__ b2,
        const float* __restrict__ c3w, const float* __restrict__ c3b,
        const float* __restrict__ g3, const float* __restrict__ b3,
        const float* __restrict__ w1, const float* __restrict__ w2,
        const float* __restrict__ dw,
        const int* __restrict__ ei, const int* __restrict__ batch,
        float* __restrict__ wf1t, float* __restrict__ bf1,
        unsigned short* __restrict__ wB2, float* __restrict__ bf2c,
        unsigned short* __restrict__ wB3, float* __restrict__ bf3c,
        unsigned short* __restrict__ wt1, unsigned short* __restrict__ wt2,
        float* __restrict__ dwt,
        int* __restrict__ count, float* __restrict__ dinv,
        int* __restrict__ cnt, float* __restrict__ lacc,
        int* __restrict__ offs, int* __restrict__ cur) {
    __shared__ int cntL[N_];
    __shared__ int bcnt[B_];
    __shared__ int part[256];
    int bid = blockIdx.x, tid = threadIdx.x;
    const float rs = rsqrtf(1.f + EPS_);
    if (bid == 0) {
        // ---- degree + batch histograms in LDS ----
        for (int i = tid; i < N_; i += 256) cntL[i] = 0;
        if (tid < B_) bcnt[tid] = 0;
        if (tid < B_ * 4) lacc[tid] = 0.f;
        __syncthreads();
#pragma unroll
        for (int it = 0; it < E_ / 256; ++it) atomicAdd(&cntL[ei[E_ + tid + 256 * it]], 1);
#pragma unroll
        for (int it = 0; it < N_ / 256; ++it) atomicAdd(&bcnt[batch[tid + 256 * it]], 1);
        __syncthreads();
        // ---- scan (8 per thread) ----
        int loc[8];
        int s = 0;
        int base = tid * 8;
#pragma unroll
        for (int j = 0; j < 8; ++j) { loc[j] = cntL[base + j]; s += loc[j]; }
        part[tid] = s;
        __syncthreads();
        for (int o = 1; o < 256; o <<= 1) {
            int add = (tid >= o) ? part[tid - o] : 0;
            __syncthreads();
            part[tid] += add;
            __syncthreads();
        }
        int run = part[tid] - s;
#pragma unroll
        for (int j = 0; j < 8; ++j) {
            offs[base + j] = run;
            cur[base + j] = run;
            count[base + j] = loc[j];
            dinv[base + j] = rsqrtf((float)(loc[j] + 1));
            run += loc[j];
        }
        if (tid < B_) cnt[tid] = bcnt[tid];
    } else if (bid == 1) {
        // ---- conv1 weights + biases + conv2 B-operand ----
        for (int i = tid; i < C1_ * K1_; i += 256) {
            int k = i >> 3, c = i & 7;
            wf1t[i] = c1w[c * K1_ + k] * g1[c] * rs;
        }
        if (tid < C1_) bf1[tid] = c1b[tid] * g1[tid] * rs + b1[tid];
        if (tid >= 32 && tid < 48) { int c = tid - 32; bf2c[c] = c2b[c] * g2[c] * rs + b2[c]; }
        if (tid >= 64 && tid < 96) { int c = tid - 64; bf3c[c] = c3b[c] * g3[c] * rs + b3[c]; }
        // wB2[g][c2][ph*8+c1]: fused conv2 taps m=4g+ph (0 if m>=18)
        for (int i = tid; i < 5 * C2_ * 32; i += 256) {
            int g = i >> 9, rem = i & 511;
            int c2 = rem >> 5, k32 = rem & 31;
            int ph = k32 >> 3, c1 = k32 & 7;
            int m = 4 * g + ph;
            float s = 0.f;
            if (m < M2_) {
                for (int k = 0; k < K2_; ++k) { int d = m - k; if (d >= 0 && d <= 3) s += c2w[(c2 * C1_ + c1) * K2_ + k]; }
                s *= g2[c2] * rs * 0.25f;
            }
            wB2[i] = f2bf(s);
        }
    } else if (bid == 2) {
        // ---- conv3 B-operand + gcn1 weights ----
        for (int i = tid; i < 5 * C3_ * 32; i += 256) {
            int g = i >> 10, rem = i & 1023;
            int c3 = rem >> 5, j = rem & 31;
            int c2 = j & 15, mloc = j >> 4;
            int m = 2 * g + mloc;
            float s = 0.f;
            for (int k = 0; k < K3_; ++k) { int d = m - k; if (d >= 0 && d <= 3) s += c3w[(c3 * C2_ + c2) * K3_ + k]; }
            wB3[i] = f2bf(s * g3[c3] * rs * 0.25f);
        }
        for (int i = tid; i < C3_ * D_; i += 256) { int d = i >> 5, c = i & 31; wt1[i] = f2bf(w1[c * D_ + d]); }
    } else if (bid == 3) {
        // ---- gcn2 weights (128x128 transpose) ----
        for (int i = tid; i < D_ * D_; i += 256) { int d2 = i >> 7, d1 = i & 127; wt2[i] = f2bf(w2[d1 * D_ + d2]); }
    } else {
        // ---- dense_w transpose: coalesced READS of dw, scattered writes ----
        int seg = bid - 4;                       // 0..7
        int start = seg * (T2_ * D_ * 4 / 8);    // 3904 each
        for (int q = start + tid; q < start + T2_ * D_ * 4 / 8; q += 256) {
            int col = q / (T2_ * 4);
            int r = q - col * (T2_ * 4);
            int t = r >> 2, j = r & 3;
            dwt[(t * D_ + col) * 4 + j] = dw[q];
        }
    }
}

// ====== k_fillconv <<<64+2048>>>: blocks 0-63 CSR fill; blocks 64+ conv stack ======
__global__ __launch_bounds__(256) void k_fillconv(const float* __restrict__ x,
        const float* __restrict__ pos,
        const float* __restrict__ pw1, const float* __restrict__ pb1,
        const float* __restrict__ pw2, const float* __restrict__ pb2,
        const float* __restrict__ wf1t, const float* __restrict__ bf1,
        const unsigned short* __restrict__ wB2g, const float* __restrict__ bf2c,
        const unsigned short* __restrict__ wB3g, const float* __restrict__ bf3c,
        const int* __restrict__ ei, int* __restrict__ cur, int* __restrict__ csr,
        unsigned short* __restrict__ h3) {
    __shared__ __align__(16) float xin[T_ + 32];               // halo 12 + pad
    __shared__ __align__(16) float wl1[C1_ * K1_];
    __shared__ __align__(16) unsigned short xs2[260 * 40];     // 20.8 KB
    __shared__ __align__(16) unsigned short xs3[66 * 72];      // 9.5 KB
    __shared__ float hid[32], pes[32];
    int bid = blockIdx.x, tid = threadIdx.x;
    if (bid < FILLB_) {
        int e = bid * 256 + tid;
        int d = ei[E_ + e], src = ei[e];
        int p = atomicAdd(&cur[d], 1);
        csr[p] = src;
        return;
    }
    int n = bid - FILLB_;
    int wid = tid >> 6, lane = tid & 63;
    int lrow = lane & 15, lk = lane >> 4;
    for (int i = tid; i < T_ + 32; i += 256) {
        int gi = i - 12;
        xin[i] = (gi >= 0 && gi < T_) ? x[n * T_ + gi] : 0.f;
    }
    if (tid < C1_ * K1_) wl1[tid] = wf1t[tid];
    if (tid < 32) {
        float p0 = pos[n * 3], p1 = pos[n * 3 + 1], p2 = pos[n * 3 + 2];
        hid[tid] = fmaxf(p0 * pw1[tid] + p1 * pw1[32 + tid] + p2 * pw1[64 + tid] + pb1[tid], 0.f);
    }
    float bl1r[C1_];
#pragma unroll
    for (int c = 0; c < C1_; ++c) bl1r[c] = bf1[c];
    __syncthreads();
    if (tid < 32) {
        float o = pb2[tid];
#pragma unroll
        for (int cc = 0; cc < 32; ++cc) o += hid[cc] * pw2[cc * 32 + tid];
        pes[tid] = o;
    }
    // ---- conv1 (f32 VALU) -> xs2 bf16 fragments ----
#pragma unroll
    for (int it = 0; it < 4; ++it) {
        int t = tid + 256 * it;
        float a[C1_];
#pragma unroll
        for (int c = 0; c < C1_; ++c) a[c] = bl1r[c];
#pragma unroll
        for (int k = 0; k < K1_; ++k) {
            float xv = xin[t + k];
            const f32x4* wp = (const f32x4*)&wl1[k * C1_];
            f32x4 w0 = wp[0], w1v = wp[1];
#pragma unroll
            for (int j = 0; j < 4; ++j) { a[j] += w0[j] * xv; a[4 + j] += w1v[j] * xv; }
        }
        int u = t >> 2, ph = t & 3;
        bf16x8 sv;
#pragma unroll
        for (int c = 0; c < C1_; ++c) sv[c] = (short)f2bf(fmaxf(a[c], 0.f));
        *(bf16x8*)&xs2[u * 40 + ph * 8] = sv;
    }
    __syncthreads();
    // ---- conv2 via MFMA (B from L2), epilogue -> xs3 fragments ----
    {
        bf16x8 bfr[5];
#pragma unroll
        for (int g = 0; g < 5; ++g)
            bfr[g] = *(const bf16x8*)(wB2g + g * 512 + lrow * 32 + lk * 8);
        float bb = bf2c[lrow];
#pragma unroll
        for (int mt = 0; mt < 4; ++mt) {
            int p0 = (wid * 4 + mt) * 16;
            f32x4 c4 = {0.f, 0.f, 0.f, 0.f};
#pragma unroll
            for (int g = 0; g < 5; ++g) {
                bf16x8 af = *(const bf16x8*)&xs2[(p0 + lrow + g) * 40 + lk * 8];
                c4 = __builtin_amdgcn_mfma_f32_16x16x32_bf16(af, bfr[g], c4, 0, 0, 0);
            }
            int urow = (p0 >> 2) + lk;
#pragma unroll
            for (int r = 0; r < 4; ++r)
                xs3[urow * 72 + r * 16 + lrow] = f2bf(fmaxf(c4[r] + bb, 0.f));
        }
    }
    __syncthreads();
    // ---- conv3 via MFMA (B from L2) + bias + relu + pe -> h3 ----
    {
        int t0 = wid * 16;
        f32x4 acc[2];
        acc[0] = f32x4{0.f, 0.f, 0.f, 0.f};
        acc[1] = f32x4{0.f, 0.f, 0.f, 0.f};
        bf16x8 af[5];
#pragma unroll
        for (int g = 0; g < 5; ++g)
            af[g] = *(const bf16x8*)&xs3[(t0 + lrow + (g >> 1)) * 72 + (g & 1) * 32 + lk * 8];
#pragma unroll
        for (int nn = 0; nn < 2; ++nn) {
#pragma unroll
            for (int g = 0; g < 5; ++g) {
                bf16x8 bf = *(const bf16x8*)(wB3g + g * 1024 + (nn * 16 + lrow) * 32 + lk * 8);
                acc[nn] = __builtin_amdgcn_mfma_f32_16x16x32_bf16(af[g], bf, acc[nn], 0, 0, 0);
            }
        }
#pragma unroll
        for (int nn = 0; nn < 2; ++nn) {
            int c3 = nn * 16 + lrow;
            float b3v = bf3c[c3];
            float pev = pes[c3];
#pragma unroll
            for (int r = 0; r < 4; ++r) {
                int t = t0 + lk * 4 + r;
                if (t < T2_)
                    h3[(size_t)n * H3E_ + t * C3_ + c3] = f2bf(fmaxf(acc[nn][r] + b3v, 0.f) + pev);
            }
        }
    }
}

// ====== gather aggregation layer 1 (bf16 in/out, f32 accum, both dinv folded) ======
template <int NG>
__global__ __launch_bounds__(256) void k_agg_bf(const unsigned short* __restrict__ h,
        const int* __restrict__ off, const int* __restrict__ cnt, const int* __restrict__ csr,
        const float* __restrict__ dinv, unsigned short* __restrict__ out) {
    int n = blockIdx.x, tid = threadIdx.x;
    float acc[8];
    float dn = dinv[n];
    const bf16x8* self = (const bf16x8*)(h + (size_t)n * NG * 8);
    if (tid < NG) {
        bf16x8 v = self[tid];
#pragma unroll
        for (int j = 0; j < 8; ++j) acc[j] = dn * bf2f((unsigned short)v[j]);
    }
    int st = off[n], c = cnt[n];
    for (int i = 0; i < c; ++i) {
        int sn = csr[st + i];
        float f = dinv[sn];
        if (tid < NG) {
            bf16x8 v = ((const bf16x8*)(h + (size_t)sn * NG * 8))[tid];
#pragma unroll
            for (int j = 0; j < 8; ++j) acc[j] += f * bf2f((unsigned short)v[j]);
        }
    }
    if (tid < NG) {
        bf16x8 v;
#pragma unroll
        for (int j = 0; j < 8; ++j) v[j] = (short)f2bf(acc[j] * dn);
        ((bf16x8*)(out + (size_t)n * NG * 8))[tid] = v;
    }
}

// ====== FUSED agg2+gemm1+gemm2+dense projection, one block per node ======
// phase1: acc1 = dinv[n]*sum_s dinv[s]*relu(agg1[s]@W1+b1)     (wave = 16 rows x 128 cols)
// phase2: per-wave LDS transpose -> A-fragments; h2f = relu(acc1@W2+b2)
// phase3: logits[batch[n]] += sum_t,d h2f[t][d]*dwt[t][d][:]   (shfl-reduce + 4 atomics)
__global__ __launch_bounds__(256) void k_agg_gemm12f(const unsigned short* __restrict__ agg1,
        const unsigned short* __restrict__ wt1, const float* __restrict__ bias1,
        const unsigned short* __restrict__ wt2, const float* __restrict__ bias2,
        const float* __restrict__ dwt, const int* __restrict__ batch,
        const int* __restrict__ off, const int* __restrict__ cnt, const int* __restrict__ csr,
        const float* __restrict__ dinv, float* __restrict__ lacc) {
    __shared__ __align__(16) unsigned short t2[4][16][136];   // per-wave transpose tile, 17.4 KB
    __shared__ float wsum[4][4];
    int n = blockIdx.x, tid = threadIdx.x;
    int wid = tid >> 6, lane = tid & 63;
    int lrow = lane & 15, lk = lane >> 4;
    // ---- phase 1: agg + gemm1 (A read once per wave) ----
    {
        bf16x8 bfr[8];
        float bv[8];
#pragma unroll
        for (int nn = 0; nn < 8; ++nn) {
            int col = nn * 16 + lrow;
            bfr[nn] = *(const bf16x8*)&wt1[col * 32 + lk * 8];
            bv[nn] = bias1[col];
        }
        f32x4 acc[8];
#pragma unroll
        for (int nn = 0; nn < 8; ++nn) acc[nn] = f32x4{0.f, 0.f, 0.f, 0.f};
        int st = off[n], c = cnt[n];
        int arow_off = (wid * 16 + lrow) * 32 + lk * 8;
        for (int i = -1; i < c; ++i) {
            int s = (i < 0) ? n : csr[st + i];
            float f = dinv[s];
            bf16x8 af = *(const bf16x8*)(agg1 + (size_t)s * H3E_ + arow_off);
#pragma unroll
            for (int nn = 0; nn < 8; ++nn) {
                f32x4 t4 = {0.f, 0.f, 0.f, 0.f};
                t4 = __builtin_amdgcn_mfma_f32_16x16x32_bf16(af, bfr[nn], t4, 0, 0, 0);
#pragma unroll
                for (int r = 0; r < 4; ++r)
                    acc[nn][r] += f * fmaxf(t4[r] + bv[nn], 0.f);
            }
        }
        float dn = dinv[n];
        // write C-layout tile into per-wave LDS (row = lk*4+r, col = nn*16+lrow)
#pragma unroll
        for (int nn = 0; nn < 8; ++nn) {
#pragma unroll
            for (int r = 0; r < 4; ++r)
                t2[wid][lk * 4 + r][nn * 16 + lrow] = f2bf(acc[nn][r] * dn);
        }
    }
    // ---- phase 2: gemm2 from per-wave LDS tile (no cross-wave barrier needed) ----
    f32x4 acc2[8];
#pragma unroll
    for (int nn = 0; nn < 8; ++nn) acc2[nn] = f32x4{0.f, 0.f, 0.f, 0.f};
#pragma unroll
    for (int ks = 0; ks < 4; ++ks) {
        bf16x8 a = *(const bf16x8*)&t2[wid][lrow][ks * 32 + lk * 8];
#pragma unroll
        for (int nn = 0; nn < 8; ++nn) {
            bf16x8 b = *(const bf16x8*)&wt2[((size_t)(nn * 16 + lrow)) * D_ + ks * 32 + lk * 8];
            acc2[nn] = __builtin_amdgcn_mfma_f32_16x16x32_bf16(a, b, acc2[nn], 0, 0, 0);
        }
    }
    // ---- phase 3: dense projection + block reduce + atomics ----
    f32x4 s = {0.f, 0.f, 0.f, 0.f};
#pragma unroll
    for (int r = 0; r < 4; ++r) {
        int t = wid * 16 + lk * 4 + r;
        if (t < T2_) {
#pragma unroll
            for (int nn = 0; nn < 8; ++nn) {
                int col = nn * 16 + lrow;
                float v = fmaxf(acc2[nn][r] + bias2[col], 0.f);
                f32x4 w = *(const f32x4*)(dwt + ((size_t)t * D_ + col) * 4);
                s += v * w;
            }
        }
    }
    // wave shuffle reduce (64 lanes)
#pragma unroll
    for (int m = 32; m > 0; m >>= 1) {
#pragma unroll
        for (int j = 0; j < 4; ++j) s[j] += __shfl_xor(s[j], m, 64);
    }
    if (lane == 0) {
#pragma unroll
        for (int j = 0; j < 4; ++j) wsum[wid][j] = s[j];
    }
    __syncthreads();
    if (tid < 4) {
        float tot = wsum[0][tid] + wsum[1][tid] + wsum[2][tid] + wsum[3][tid];
        atomicAdd(&lacc[batch[n] * 4 + tid], tot);
    }
}

// ============== tiny final: /cnt, +db, log_softmax ==============
__global__ void k_final2(const float* __restrict__ acc, const int* __restrict__ cnt,
                         const float* __restrict__ db, float* __restrict__ out) {
    int b = threadIdx.x;
    if (b < B_) {
        float inv = 1.f / fmaxf((float)cnt[b], 1.f);
        float l[4];
#pragma unroll
        for (int j = 0; j < 4; ++j) l[j] = acc[b * 4 + j] * inv + db[j];
        float m = fmaxf(fmaxf(l[0], l[1]), fmaxf(l[2], l[3]));
        float s = expf(l[0] - m) + expf(l[1] - m) + expf(l[2] - m) + expf(l[3] - m);
        float ls = m + logf(s);
#pragma unroll
        for (int j = 0; j < 4; ++j) out[b * 4 + j] = l[j] - ls;
    }
}

// ======================= launch =======================
extern "C" void kernel_launch(void* const* d_in, const int* in_sizes, int n_in,
                              void* d_out, int out_size, void* d_ws, size_t ws_size,
                              hipStream_t stream) {
    const float* x       = (const float*)d_in[0];
    const float* pos     = (const float*)d_in[1];
    const float* conv1_w = (const float*)d_in[2];
    const float* conv1_b = (const float*)d_in[3];
    const float* bn1_g   = (const float*)d_in[4];
    const float* bn1_b   = (const float*)d_in[5];
    const float* conv2_w = (const float*)d_in[6];
    const float* conv2_b = (const float*)d_in[7];
    const float* bn2_g   = (const float*)d_in[8];
    const float* bn2_b   = (const float*)d_in[9];
    const float* conv3_w = (const float*)d_in[10];
    const float* conv3_b = (const float*)d_in[11];
    const float* bn3_g   = (const float*)d_in[12];
    const float* bn3_b   = (const float*)d_in[13];
    const float* pos_w1  = (const float*)d_in[14];
    const float* pos_b1  = (const float*)d_in[15];
    const float* pos_w2  = (const float*)d_in[16];
    const float* pos_b2  = (const float*)d_in[17];
    const float* gcn1_w  = (const float*)d_in[18];
    const float* gcn1_b  = (const float*)d_in[19];
    const float* gcn2_w  = (const float*)d_in[20];
    const float* gcn2_b  = (const float*)d_in[21];
    const float* dense_w = (const float*)d_in[22];
    const float* dense_b = (const float*)d_in[23];
    const int*   eidx    = (const int*)d_in[24];
    const int*   batch   = (const int*)d_in[25];
    float* out = (float*)d_out;
    char* ws = (char*)d_ws;

    size_t off = 0;
    auto alloc = [&](size_t bytes) { size_t o = off; off += (bytes + 255) & ~(size_t)255; return o; };
    size_t o_h3     = alloc((size_t)N_ * H3E_ * 2);              // 8 MB bf16
    size_t o_agg1   = alloc(((size_t)N_ * H3E_ + 2048) * 2);     // 8 MB bf16 (+slack for row-64 overreads)
    size_t o_lacc   = alloc((size_t)B_ * 4 * 4);
    size_t o_count  = alloc((size_t)N_ * 4);
    size_t o_off    = alloc((size_t)N_ * 4);
    size_t o_cur    = alloc((size_t)N_ * 4);
    size_t o_dinv   = alloc((size_t)N_ * 4);
    size_t o_csr    = alloc((size_t)E_ * 4);
    size_t o_cnt    = alloc((size_t)B_ * 4);
    size_t o_wf1t   = alloc((size_t)C1_ * K1_ * 4);
    size_t o_bf1    = alloc((size_t)C1_ * 4);
    size_t o_wB2    = alloc((size_t)5 * C2_ * 32 * 2);
    size_t o_bf2c   = alloc((size_t)C2_ * 4);
    size_t o_wB3    = alloc((size_t)5 * C3_ * 32 * 2);
    size_t o_bf3c   = alloc((size_t)C3_ * 4);
    size_t o_wt1    = alloc((size_t)C3_ * D_ * 2);
    size_t o_wt2    = alloc((size_t)D_ * D_ * 2);
    size_t o_dwt    = alloc((size_t)T2_ * D_ * 4 * 4);

    unsigned short* h3   = (unsigned short*)(ws + o_h3);
    unsigned short* agg1 = (unsigned short*)(ws + o_agg1);
    float* lacc   = (float*)(ws + o_lacc);
    int*   count  = (int*)(ws + o_count);
    int*   offs   = (int*)(ws + o_off);
    int*   cur    = (int*)(ws + o_cur);
    float* dinv   = (float*)(ws + o_dinv);
    int*   csr    = (int*)(ws + o_csr);
    int*   cnt    = (int*)(ws + o_cnt);
    float* wf1t   = (float*)(ws + o_wf1t);
    float* bf1    = (float*)(ws + o_bf1);
    unsigned short* wB2 = (unsigned short*)(ws + o_wB2);
    float* bf2c   = (float*)(ws + o_bf2c);
    unsigned short* wB3 = (unsigned short*)(ws + o_wB3);
    float* bf3c   = (float*)(ws + o_bf3c);
    unsigned short* wt1 = (unsigned short*)(ws + o_wt1);
    unsigned short* wt2 = (unsigned short*)(ws + o_wt2);
    float* dwt    = (float*)(ws + o_dwt);

    k_init<<<12, 256, 0, stream>>>(conv1_w, conv1_b, bn1_g, bn1_b,
                                   conv2_w, conv2_b, bn2_g, bn2_b,
                                   conv3_w, conv3_b, bn3_g, bn3_b,
                                   gcn1_w, gcn2_w, dense_w, eidx, batch,
                                   wf1t, bf1, wB2, bf2c, wB3, bf3c, wt1, wt2, dwt,
                                   count, dinv, cnt, lacc, offs, cur);
    k_fillconv<<<FILLB_ + N_, 256, 0, stream>>>(x, pos, pos_w1, pos_b1, pos_w2, pos_b2,
                                                wf1t, bf1, wB2, bf2c, wB3, bf3c,
                                                eidx, cur, csr, h3);
    k_agg_bf<H3E_ / 8><<<N_, 256, 0, stream>>>(h3, offs, count, csr, dinv, agg1);
    k_agg_gemm12f<<<N_, 256, 0, stream>>>(agg1, wt1, gcn1_b, wt2, gcn2_b, dwt, batch,
                                          offs, count, csr, dinv, lacc);
    k_final2<<<1, 64, 0, stream>>>(lacc, cnt, dense_b, out);
}